// Round 1
// 426.453 us; speedup vs baseline: 1.0470x; 1.0470x over previous
//
#include <hip/hip_runtime.h>
#include <cfloat>
#include <climits>
#include <math.h>

// Problem constants
#define BB 2048
#define NN 50000
#define DD 128
#define KK 20

// K1 selection geometry
#define NSLICE 16
#define NSL 3125          // NN / NSLICE (exact)
#define NTILE 98          // ceil(NSL/32); tile 97 partial (21 valid entries)
#define LK 8              // per-lane sorted key slots
#define SLC 16            // per (row,slice) stored candidates (2 lanes x LK)
#define CAND 256          // NSLICE * SLC per row per task
#define K1W 4             // waves per k1 block (tile-split, LDS-merged)

// out layout (floats): vals_cos, ind_cos, labels_rot, vals_euc, ind_euc, labels_trans
#define O_VC 0
#define O_IC 40960
#define O_LR 81920
#define O_VE 122880
#define O_IE 163840
#define O_LT 204800

// ws layout (bytes): Bbf 25.6MB | bq2 200KB | candU 2.1MB = 27.90MB
#define WS_BBF   0
#define WS_BQ2   25600000
#define WS_CAND  25800000

typedef short v8s __attribute__((ext_vector_type(8)));
typedef float v16f __attribute__((ext_vector_type(16)));

union U4V8 { uint4 u; v8s v; };

__device__ __forceinline__ unsigned int bf16rne(float f) {
    unsigned int x = __float_as_uint(f);
    return (x + 0x7FFFu + ((x >> 16) & 1u)) >> 16;
}
// monotone fp32 -> u32 (total order); bit-identical to the 4-op version
__device__ __forceinline__ unsigned int sortkey(float s) {
    unsigned int b = __float_as_uint(s);
    return b ^ ((unsigned int)((int)b >> 31) | 0x80000000u);
}
// single-instruction sorted-insert step: for a<=b<=..., med3(k, key[u], key[u+1])
// == min(key[u+1], max(k, key[u])) when key[u] <= key[u+1] (sortedness invariant)
__device__ __forceinline__ unsigned int med3u(unsigned int a, unsigned int b, unsigned int c) {
    unsigned int d;
    asm("v_med3_u32 %0, %1, %2, %3" : "=v"(d) : "v"(a), "v"(b), "v"(c));
    return d;
}
__device__ __forceinline__ void ins8(unsigned int (&key)[LK], unsigned int k) {
    #pragma unroll
    for (int u = 0; u < LK - 1; u++) key[u] = med3u(k, key[u], key[u + 1]);
    key[LK - 1] = max(k, key[LK - 1]);
}

// ---------------- K0: build bf16 book (cos: b, euc: 2b) + packed -bq (hi/lo bf16) ----
// 32 lanes per entry; 2 entries per wave; 8 entries per block.
__global__ __launch_bounds__(256) void k_cvt2(const float* __restrict__ bR,
                                              const float* __restrict__ bT,
                                              unsigned int* __restrict__ Bbf,
                                              unsigned int* __restrict__ bq2)
{
    const int t = threadIdx.x;
    const int job = (blockIdx.x * 256 + t) >> 5;     // 0..99999
    const int l = t & 31;
    const int task = job >= NN;
    const int e = job - task * NN;

    const float* src = (task ? bT : bR) + (size_t)e * DD + l * 4;
    float4 v = *reinterpret_cast<const float4*>(src);
    float sq = v.x * v.x + v.y * v.y + v.z * v.z + v.w * v.w;   // from ORIGINAL b
    const float sc = task ? 2.f : 1.f;
    uint2 o;
    o.x = bf16rne(v.x * sc) | (bf16rne(v.y * sc) << 16);
    o.y = bf16rne(v.z * sc) | (bf16rne(v.w * sc) << 16);
    reinterpret_cast<uint2*>(Bbf)[(size_t)(task * NN + e) * 32 + l] = o;

    if (task) {
        #pragma unroll
        for (int m = 1; m < 32; m <<= 1) sq += __shfl_xor(sq, m, 64);  // stays in 32-group
        if (l == 0) {
            unsigned int hi = bf16rne(sq);
            float fhi = __uint_as_float(hi << 16);
            unsigned int lo = bf16rne(sq - fhi);
            bq2[e] = (hi ^ 0x8000u) | ((lo ^ 0x8000u) << 16);   // packed (-bq_hi, -bq_lo)
        }
    }
}

// ---------------- K1: swapped-operand MFMA scoring + in-register branchless top-8 ----
// K1W waves per (slice, rowgroup-of-32, task); wave w handles tiles w, w+K1W, ...
// then waves 1..3 dump their sorted-8 lists to LDS and wave 0 merges (top-8 of the
// union of per-chunk top-8s == top-8 of the whole stream -> candU bit-identical to
// the single-wave version). A = book entries (m), B = z rows (n).
// C layout: n = lane&31 (z-row per lane), m = (reg&3)+8*(reg>>2)+4*(lane>>5).
// Key = sortkey(score)&0xFFFF0000 | n (n<50000 fits 16 bits; K2 re-ranks exactly).
__global__ __launch_bounds__(256, 6) void k1_sel(
    const float* __restrict__ zR, const float* __restrict__ zT,
    const unsigned int* __restrict__ Bbf,
    const unsigned int* __restrict__ bq2,
    uint4* __restrict__ candU)
{
    const int slice = blockIdx.x;       // 0..15  (slice%8 -> XCD L2 locality)
    const int rg    = blockIdx.y;       // 0..63
    const int task  = blockIdx.z;
    const int w     = threadIdx.x >> 6; // wave 0..3
    const int lane  = threadIdx.x & 63;
    const int col   = lane & 31;
    const int h     = lane >> 5;

    __shared__ unsigned int smk[K1W - 1][64][LK];   // 6 KB

    // ---- persistent z-frags (B operand): row = rg*32+col, k = 16q+8h..+8 ----
    const float* zp = (task ? zT : zR) + (size_t)(rg * 32 + col) * DD;
    v8s zf[9];
    #pragma unroll
    for (int q = 0; q < 8; q++) {
        float4 u0 = *reinterpret_cast<const float4*>(zp + q * 16 + h * 8);
        float4 u1 = *reinterpret_cast<const float4*>(zp + q * 16 + h * 8 + 4);
        U4V8 c;
        c.u.x = bf16rne(u0.x) | (bf16rne(u0.y) << 16);
        c.u.y = bf16rne(u0.z) | (bf16rne(u0.w) << 16);
        c.u.z = bf16rne(u1.x) | (bf16rne(u1.y) << 16);
        c.u.w = bf16rne(u1.z) | (bf16rne(u1.w) << 16);
        zf[q] = c.v;
    }
    {   // 9th step: k=128,129 -> 1.0,1.0 (h=0); zeros (h=1)
        U4V8 c; c.u = make_uint4(h == 0 ? 0x3F803F80u : 0u, 0u, 0u, 0u);
        zf[8] = c.v;
    }

    unsigned int key[LK];
    #pragma unroll
    for (int u = 0; u < LK; u++) key[u] = 0u;

    const int nbase0 = slice * NSL;
    const unsigned int* bp = Bbf + (size_t)task * NN * 64;   // u32 units, 64/entry

    for (int tile = w; tile < NTILE; tile += K1W) {
        const bool tail = (tile == NTILE - 1);
        int e = nbase0 + tile * 32 + col;
        if (tail) e = min(e, nbase0 + NSL - 1);                 // clamp loads
        const unsigned int* ep = bp + (size_t)e * 64 + h * 4;

        v16f acc = {0.f,0.f,0.f,0.f, 0.f,0.f,0.f,0.f, 0.f,0.f,0.f,0.f, 0.f,0.f,0.f,0.f};
        #pragma unroll
        for (int q = 0; q < 8; q++) {
            U4V8 a; a.u = *reinterpret_cast<const uint4*>(ep + q * 8);
            acc = __builtin_amdgcn_mfma_f32_32x32x16_bf16(a.v, zf[q], acc, 0, 0, 0);
        }
        if (task) {  // 9th step folds -bq (h=0 lanes carry [-bq_hi,-bq_lo,0..])
            unsigned int bqp = bq2[e];
            U4V8 a; a.u = make_uint4(h == 0 ? bqp : 0u, 0u, 0u, 0u);
            acc = __builtin_amdgcn_mfma_f32_32x32x16_bf16(a.v, zf[8], acc, 0, 0, 0);
        }

        const int nb = nbase0 + tile * 32 + 4 * h;
        #pragma unroll
        for (int r = 0; r < 16; r++) {
            const int pat = (r & 3) + 8 * (r >> 2);             // + 4h in nb
            const int n = nb + pat;
            unsigned int k = (sortkey(acc[r]) & 0xFFFF0000u) | (unsigned int)n;
            if (tail && (tile * 32 + pat + 4 * h >= NSL)) k = 0u;  // mask invalid
            ins8(key, k);
        }
    }

    // ---- cross-wave merge: waves 1..3 publish, wave 0 folds 24 keys per lane ----
    if (w > 0) {
        #pragma unroll
        for (int u = 0; u < LK; u++) smk[w - 1][lane][u] = key[u];
    }
    __syncthreads();
    if (w == 0) {
        #pragma unroll
        for (int v = 0; v < K1W - 1; v++) {
            #pragma unroll
            for (int u = 0; u < LK; u++) ins8(key, smk[v][lane][u]);
        }

        // ---- writeout: 8 entry-indices per lane -> 16B store; 16 per (row,slice) ----
        uint4 o;
        o.x = (key[0] & 0xFFFFu) | ((key[1] & 0xFFFFu) << 16);
        o.y = (key[2] & 0xFFFFu) | ((key[3] & 0xFFFFu) << 16);
        o.z = (key[4] & 0xFFFFu) | ((key[5] & 0xFFFFu) << 16);
        o.w = (key[6] & 0xFFFFu) | ((key[7] & 0xFFFFu) << 16);
        const int row = rg * 32 + col;
        candU[((size_t)(task * BB + row) * NSLICE + slice) * 2 + h] = o;
    }
}

// ---------------- K2: exact final ranking + gather (R3-verified logic, CAND=256) ----
__global__ __launch_bounds__(256) void k2_final(
    const float* __restrict__ Zr, const float* __restrict__ Zt,
    const float* __restrict__ Br, const float* __restrict__ Bt,
    const float* __restrict__ rotB, const float* __restrict__ transB,
    const unsigned short* __restrict__ candU16,
    float* __restrict__ out)
{
    const int row = blockIdx.x;
    const int task = blockIdx.y;
    const int t = threadIdx.x;
    const float* __restrict__ Z  = task ? Zt : Zr;
    const float* __restrict__ Bk = task ? Bt : Br;

    __shared__ __align__(16) float zrow[DD];
    __shared__ int sel[CAND];
    __shared__ double dotp[CAND * 8];
    __shared__ double sval[KK];
    __shared__ int sidx[KK];
    __shared__ float sv[CAND];

    if (t < DD) zrow[t] = Z[(size_t)row * DD + t];
    sel[t] = (int)candU16[((size_t)task * BB + row) * CAND + t];
    __syncthreads();

    if (task == 0) {
        // ---- cos: exact fp64 rescore + top-20 ----
        #pragma unroll
        for (int it = 0; it < 8; it++) {
            int idx = t + it * 256;
            int cnd = idx >> 3, part = idx & 7;
            int n = sel[cnd];
            const float* brow = Bk + (size_t)n * DD + part * 16;
            double dp = 0.0;
            #pragma unroll
            for (int q = 0; q < 4; q++) {
                float4 b4 = *reinterpret_cast<const float4*>(brow + q * 4);
                const int k = part * 16 + q * 4;
                dp += (double)zrow[k + 0] * (double)b4.x + (double)zrow[k + 1] * (double)b4.y
                    + (double)zrow[k + 2] * (double)b4.z + (double)zrow[k + 3] * (double)b4.w;
            }
            dotp[idx] = dp;
        }
        __syncthreads();

        if (t < 64) {
            double zq = (double)zrow[t] * (double)zrow[t]
                      + (double)zrow[t + 64] * (double)zrow[t + 64];
            #pragma unroll
            for (int m = 1; m < 64; m <<= 1) zq += __shfl_xor(zq, m, 64);

            double s[4]; int ix[4];
            #pragma unroll
            for (int j = 0; j < 4; j++) {
                const int c = t + 64 * j;
                double dot = 0.0;
                #pragma unroll
                for (int p = 0; p < 8; p++) dot += dotp[c * 8 + p];
                s[j] = dot; ix[j] = sel[c];
            }

            for (int rd = 0; rd < KK; rd++) {
                double bs = s[0]; int bn = ix[0];
                #pragma unroll
                for (int j = 1; j < 4; j++)
                    if (s[j] > bs || (s[j] == bs && ix[j] < bn)) { bs = s[j]; bn = ix[j]; }
                #pragma unroll
                for (int m = 1; m < 64; m <<= 1) {
                    double os = __shfl_xor(bs, m, 64);
                    int on = __shfl_xor(bn, m, 64);
                    if (os > bs || (os == bs && on < bn)) { bs = os; bn = on; }
                }
                #pragma unroll
                for (int j = 0; j < 4; j++) if (ix[j] == bn) s[j] = -DBL_MAX;  // pop (n unique)
                if (t == 0) { sval[rd] = bs; sidx[rd] = bn; }
            }
            if (t == 0) dotp[0] = zq;
        }
        __syncthreads();

        if (t < KK) {
            const double zq = dotp[0];
            const int n = sidx[t];
            const int o = row * KK + t;
            out[O_VC + o] = (float)(sval[t] / sqrt(zq));
            out[O_IC + o] = (float)n;
            out[O_LR + o] = rotB[n];
        }
    } else {
        // ---- euc: bit-exact numpy-fp32 emulation (verified R3) ----
        {
            const int n = sel[t];
            const float* brow = Bk + (size_t)n * DD;
            float L[4], r[8], q[8];
            #pragma unroll
            for (int u = 0; u < 4; u++) L[u] = 0.f;
            #pragma unroll
            for (int u = 0; u < 8; u++) { r[u] = 0.f; q[u] = 0.f; }
            #pragma unroll
            for (int c4 = 0; c4 < 32; c4++) {
                float4 b4 = *reinterpret_cast<const float4*>(brow + c4 * 4);
                float4 z4 = *reinterpret_cast<const float4*>(&zrow[c4 * 4]);
                const int m8 = (c4 & 1) * 4;
                L[0] = __fadd_rn(L[0], __fmul_rn(z4.x, b4.x));
                L[1] = __fadd_rn(L[1], __fmul_rn(z4.y, b4.y));
                L[2] = __fadd_rn(L[2], __fmul_rn(z4.z, b4.z));
                L[3] = __fadd_rn(L[3], __fmul_rn(z4.w, b4.w));
                r[m8 + 0] = __fadd_rn(r[m8 + 0], __fmul_rn(b4.x, b4.x));
                r[m8 + 1] = __fadd_rn(r[m8 + 1], __fmul_rn(b4.y, b4.y));
                r[m8 + 2] = __fadd_rn(r[m8 + 2], __fmul_rn(b4.z, b4.z));
                r[m8 + 3] = __fadd_rn(r[m8 + 3], __fmul_rn(b4.w, b4.w));
                q[m8 + 0] = __fadd_rn(q[m8 + 0], __fmul_rn(z4.x, z4.x));
                q[m8 + 1] = __fadd_rn(q[m8 + 1], __fmul_rn(z4.y, z4.y));
                q[m8 + 2] = __fadd_rn(q[m8 + 2], __fmul_rn(z4.z, z4.z));
                q[m8 + 3] = __fadd_rn(q[m8 + 3], __fmul_rn(z4.w, z4.w));
            }
            const float dot = __fadd_rn(__fadd_rn(L[0], L[2]), __fadd_rn(L[1], L[3]));
            const float bqv = __fadd_rn(__fadd_rn(__fadd_rn(r[0], r[1]), __fadd_rn(r[2], r[3])),
                                        __fadd_rn(__fadd_rn(r[4], r[5]), __fadd_rn(r[6], r[7])));
            const float zqv = __fadd_rn(__fadd_rn(__fadd_rn(q[0], q[1]), __fadd_rn(q[2], q[3])),
                                        __fadd_rn(__fadd_rn(q[4], q[5]), __fadd_rn(q[6], q[7])));
            sv[t] = __fsub_rn(__fsub_rn(__fmul_rn(2.0f, dot), zqv), bqv);
        }
        __syncthreads();

        if (t < 64) {
            float s[4]; int ix[4];
            #pragma unroll
            for (int j = 0; j < 4; j++) { s[j] = sv[t + 64 * j]; ix[j] = sel[t + 64 * j]; }

            for (int rd = 0; rd < KK; rd++) {
                float bs = s[0]; int bn = ix[0];
                #pragma unroll
                for (int j = 1; j < 4; j++)
                    if (s[j] > bs || (s[j] == bs && ix[j] < bn)) { bs = s[j]; bn = ix[j]; }
                #pragma unroll
                for (int m = 1; m < 64; m <<= 1) {
                    float os = __shfl_xor(bs, m, 64);
                    int on = __shfl_xor(bn, m, 64);
                    if (os > bs || (os == bs && on < bn)) { bs = os; bn = on; }
                }
                #pragma unroll
                for (int j = 0; j < 4; j++) if (ix[j] == bn) s[j] = -FLT_MAX;
                if (t == 0) {
                    const int o = row * KK + rd;
                    out[O_VE + o] = bs;
                    out[O_IE + o] = (float)bn;
                    const int o3 = O_LT + o * 3;
                    out[o3 + 0] = transB[bn * 3 + 0];
                    out[o3 + 1] = transB[bn * 3 + 1];
                    out[o3 + 2] = transB[bn * 3 + 2];
                }
            }
        }
    }
}

// ---------------- launch ------------------------------------------------------------
extern "C" void kernel_launch(void* const* d_in, const int* in_sizes, int n_in,
                              void* d_out, int out_size, void* d_ws, size_t ws_size,
                              hipStream_t stream) {
    const float* zR = (const float*)d_in[0];
    const float* zT = (const float*)d_in[1];
    const float* bR = (const float*)d_in[2];
    const float* bT = (const float*)d_in[3];
    const float* rotB = (const float*)d_in[4];
    const float* transB = (const float*)d_in[5];
    float* out = (float*)d_out;

    char* ws = (char*)d_ws;
    unsigned int* Bbf = (unsigned int*)(ws + WS_BBF);
    unsigned int* bq2 = (unsigned int*)(ws + WS_BQ2);
    uint4* candU = (uint4*)(ws + WS_CAND);

    k_cvt2<<<12500, 256, 0, stream>>>(bR, bT, Bbf, bq2);
    k1_sel<<<dim3(NSLICE, 64, 2), 256, 0, stream>>>(zR, zT, Bbf, bq2, candU);
    k2_final<<<dim3(BB, 2), 256, 0, stream>>>(zR, zT, bR, bT, rotB, transB,
                                              (const unsigned short*)candU, out);
}

// Round 2
// 370.935 us; speedup vs baseline: 1.2037x; 1.1497x over previous
//
#include <hip/hip_runtime.h>
#include <cfloat>
#include <climits>
#include <math.h>

// Problem constants
#define BB 2048
#define NN 50000
#define DD 128
#define KK 20

// K1 selection geometry
#define NSLICE 16
#define NSL 3125          // NN / NSLICE (exact)
#define NTILE 98          // ceil(NSL/32); tile 97 partial (21 valid entries)
#define TAILV 21          // NSL - (NTILE-1)*32 valid entries in last tile
#define LK 8              // per-lane sorted key slots
#define SLC 16            // per (row,slice) stored candidates (2 lanes x LK)
#define CAND 256          // NSLICE * SLC per row per task
#define K1W 4             // waves per k1 block (tile-split, LDS-merged)

// out layout (floats): vals_cos, ind_cos, labels_rot, vals_euc, ind_euc, labels_trans
#define O_VC 0
#define O_IC 40960
#define O_LR 81920
#define O_VE 122880
#define O_IE 163840
#define O_LT 204800

// ws layout (bytes): Bbf (fragment-ordered, padded) 25.69MB | bq2 200KB | candU 2.1MB
// total 27,987,264 B  (< 28.81MB proven available in R4 of prior session)
#define WS_BBF   0
#define WS_BQ2   25690112
#define WS_CAND  25890112

typedef short v8s __attribute__((ext_vector_type(8)));
typedef float v16f __attribute__((ext_vector_type(16)));

union U4V8 { uint4 u; v8s v; };

__device__ __forceinline__ unsigned int bf16rne(float f) {
    unsigned int x = __float_as_uint(f);
    return (x + 0x7FFFu + ((x >> 16) & 1u)) >> 16;
}
// monotone fp32 -> u32 (total order)
__device__ __forceinline__ unsigned int sortkey(float s) {
    unsigned int b = __float_as_uint(s);
    return b ^ ((unsigned int)((int)b >> 31) | 0x80000000u);
}
// single-instruction sorted-insert step: med3(k, key[u], key[u+1]) ==
// min(key[u+1], max(k, key[u])) under the sortedness invariant key[u] <= key[u+1]
__device__ __forceinline__ unsigned int med3u(unsigned int a, unsigned int b, unsigned int c) {
    unsigned int d;
    asm("v_med3_u32 %0, %1, %2, %3" : "=v"(d) : "v"(a), "v"(b), "v"(c));
    return d;
}
__device__ __forceinline__ void ins8(unsigned int (&key)[LK], unsigned int k) {
    #pragma unroll
    for (int u = 0; u < LK - 1; u++) key[u] = med3u(k, key[u], key[u + 1]);
    key[LK - 1] = max(k, key[LK - 1]);
}

// ---------------- K0: build bf16 book in MFMA-FRAGMENT ORDER + packed -bq ----------
// Layout per (task,slice,tile): 8KB tile; chunk (q,h,c) = bf16(b[e][16q+8h .. +8])*sc
// at byte offset q*1024 + h*512 + c*16, where e = slice*NSL + min(32*tile+c, NSL-1)
// (tail tile duplicates the last entry -- K1 masks those scores, matching the old
// clamped-load behavior bit-for-bit). One block per tile; thread t does chunks t, t+256.
// Writes are perfectly coalesced; K1's loads become contiguous 1KB per instruction.
__global__ __launch_bounds__(256) void k_cvt2(const float* __restrict__ bR,
                                              const float* __restrict__ bT,
                                              unsigned int* __restrict__ Bbf,
                                              unsigned int* __restrict__ bq2)
{
    const int tile  = blockIdx.x;   // 0..97
    const int slice = blockIdx.y;   // 0..15
    const int task  = blockIdx.z;
    const int t = threadIdx.x;
    const float* __restrict__ src = task ? bT : bR;
    const float sc = task ? 2.f : 1.f;

    __shared__ float ps[4][64];

    unsigned int* tb = Bbf + (((size_t)(task * NSLICE + slice) * NTILE + tile) << 11);

    float partial = 0.f;
    #pragma unroll
    for (int half = 0; half < 2; half++) {
        const int x = t + half * 256;
        const int c = x & 31, hh = (x >> 5) & 1, q = x >> 6;
        const int es = slice * NSL + min(tile * 32 + c, NSL - 1);
        const float* p = src + (size_t)es * DD + q * 16 + hh * 8;
        float4 u0 = *reinterpret_cast<const float4*>(p);
        float4 u1 = *reinterpret_cast<const float4*>(p + 4);
        partial += u0.x * u0.x + u0.y * u0.y + u0.z * u0.z + u0.w * u0.w
                 + u1.x * u1.x + u1.y * u1.y + u1.z * u1.z + u1.w * u1.w;
        uint4 o;
        o.x = bf16rne(u0.x * sc) | (bf16rne(u0.y * sc) << 16);
        o.y = bf16rne(u0.z * sc) | (bf16rne(u0.w * sc) << 16);
        o.z = bf16rne(u1.x * sc) | (bf16rne(u1.y * sc) << 16);
        o.w = bf16rne(u1.z * sc) | (bf16rne(u1.w * sc) << 16);
        *reinterpret_cast<uint4*>(tb + (q << 8) + hh * 128 + c * 4) = o;
    }

    if (task) {
        // 16 partials per entry (thread t covers (q,h) and (q+4,h) of entry c=t&31)
        ps[t >> 6][t & 63] = partial;
        __syncthreads();
        if (t < 32) {
            float sq = 0.f;
            #pragma unroll
            for (int w2 = 0; w2 < 4; w2++) sq += ps[w2][t] + ps[w2][t + 32];
            unsigned int hi = bf16rne(sq);
            float fhi = __uint_as_float(hi << 16);
            unsigned int lo = bf16rne(sq - fhi);
            const int e = slice * NSL + min(tile * 32 + t, NSL - 1);
            bq2[e] = (hi ^ 0x8000u) | ((lo ^ 0x8000u) << 16);  // packed (-bq_hi, -bq_lo)
        }
    }
}

// ---------------- K1: swapped-operand MFMA scoring + in-register branchless top-8 ----
// K1W waves per (slice, rowgroup-of-32, task); wave w handles tiles w, w+K1W, ...
// LDS merge of per-wave top-8 lists (top-8 of union of per-chunk top-8s == top-8 of
// the whole stream). A-fragment loads are contiguous 1KB/instruction (K0's layout).
// Tail tile peeled out of the hot loop.
__global__ __launch_bounds__(256, 6) void k1_sel(
    const float* __restrict__ zR, const float* __restrict__ zT,
    const unsigned int* __restrict__ Bbf,
    const unsigned int* __restrict__ bq2,
    uint4* __restrict__ candU)
{
    const int slice = blockIdx.x;       // 0..15  (slice%8 -> XCD L2 locality)
    const int rg    = blockIdx.y;       // 0..63
    const int task  = blockIdx.z;
    const int w     = threadIdx.x >> 6; // wave 0..3
    const int lane  = threadIdx.x & 63;
    const int col   = lane & 31;
    const int h     = lane >> 5;

    __shared__ unsigned int smk[K1W - 1][64][LK];   // 6 KB

    // ---- persistent z-frags (B operand): row = rg*32+col, k = 16q+8h..+8 ----
    const float* zp = (task ? zT : zR) + (size_t)(rg * 32 + col) * DD;
    v8s zf[9];
    #pragma unroll
    for (int q = 0; q < 8; q++) {
        float4 u0 = *reinterpret_cast<const float4*>(zp + q * 16 + h * 8);
        float4 u1 = *reinterpret_cast<const float4*>(zp + q * 16 + h * 8 + 4);
        U4V8 c;
        c.u.x = bf16rne(u0.x) | (bf16rne(u0.y) << 16);
        c.u.y = bf16rne(u0.z) | (bf16rne(u0.w) << 16);
        c.u.z = bf16rne(u1.x) | (bf16rne(u1.y) << 16);
        c.u.w = bf16rne(u1.z) | (bf16rne(u1.w) << 16);
        zf[q] = c.v;
    }
    {   // 9th step: k=128,129 -> 1.0,1.0 (h=0); zeros (h=1)
        U4V8 c; c.u = make_uint4(h == 0 ? 0x3F803F80u : 0u, 0u, 0u, 0u);
        zf[8] = c.v;
    }

    unsigned int key[LK];
    #pragma unroll
    for (int u = 0; u < LK; u++) key[u] = 0u;

    const int nbase0 = slice * NSL;
    const unsigned int* bp = Bbf + ((size_t)(task * NSLICE + slice) * NTILE << 11) + lane * 4;

#define TILE_BODY(TILE, TAIL)                                                          \
    {                                                                                  \
        const unsigned int* tb = bp + ((size_t)(TILE) << 11);                          \
        v16f acc = {0.f,0.f,0.f,0.f, 0.f,0.f,0.f,0.f,                                  \
                    0.f,0.f,0.f,0.f, 0.f,0.f,0.f,0.f};                                 \
        _Pragma("unroll")                                                              \
        for (int q = 0; q < 8; q++) {                                                  \
            U4V8 a; a.u = *reinterpret_cast<const uint4*>(tb + (q << 8));              \
            acc = __builtin_amdgcn_mfma_f32_32x32x16_bf16(a.v, zf[q], acc, 0, 0, 0);   \
        }                                                                              \
        if (task) {                                                                    \
            int e = nbase0 + (TILE) * 32 + col;                                        \
            if (TAIL) e = min(e, nbase0 + NSL - 1);                                    \
            unsigned int bqp = bq2[e];                                                 \
            U4V8 a; a.u = make_uint4(h == 0 ? bqp : 0u, 0u, 0u, 0u);                   \
            acc = __builtin_amdgcn_mfma_f32_32x32x16_bf16(a.v, zf[8], acc, 0, 0, 0);   \
        }                                                                              \
        const int nb = nbase0 + (TILE) * 32 + 4 * h;                                   \
        _Pragma("unroll")                                                              \
        for (int r = 0; r < 16; r++) {                                                 \
            const int pat = (r & 3) + 8 * (r >> 2);                                    \
            const int n = nb + pat;                                                    \
            unsigned int k = (sortkey(acc[r]) & 0xFFFF0000u) | (unsigned int)n;        \
            if (TAIL && (pat + 4 * h >= TAILV)) k = 0u;                                \
            ins8(key, k);                                                              \
        }                                                                              \
    }

    int tile = w;
    for (; tile < NTILE - 1; tile += K1W) TILE_BODY(tile, 0)
    if (tile == NTILE - 1) TILE_BODY(tile, 1)
#undef TILE_BODY

    // ---- cross-wave merge: waves 1..3 publish, wave 0 folds 24 keys per lane ----
    if (w > 0) {
        #pragma unroll
        for (int u = 0; u < LK; u++) smk[w - 1][lane][u] = key[u];
    }
    __syncthreads();
    if (w == 0) {
        #pragma unroll
        for (int v = 0; v < K1W - 1; v++) {
            #pragma unroll
            for (int u = 0; u < LK; u++) ins8(key, smk[v][lane][u]);
        }

        // ---- writeout: 8 entry-indices per lane -> 16B store; 16 per (row,slice) ----
        uint4 o;
        o.x = (key[0] & 0xFFFFu) | ((key[1] & 0xFFFFu) << 16);
        o.y = (key[2] & 0xFFFFu) | ((key[3] & 0xFFFFu) << 16);
        o.z = (key[4] & 0xFFFFu) | ((key[5] & 0xFFFFu) << 16);
        o.w = (key[6] & 0xFFFFu) | ((key[7] & 0xFFFFu) << 16);
        const int row = rg * 32 + col;
        candU[((size_t)(task * BB + row) * NSLICE + slice) * 2 + h] = o;
    }
}

// ---------------- K2: exact final ranking + gather (R3-verified logic, CAND=256) ----
__global__ __launch_bounds__(256) void k2_final(
    const float* __restrict__ Zr, const float* __restrict__ Zt,
    const float* __restrict__ Br, const float* __restrict__ Bt,
    const float* __restrict__ rotB, const float* __restrict__ transB,
    const unsigned short* __restrict__ candU16,
    float* __restrict__ out)
{
    const int row = blockIdx.x;
    const int task = blockIdx.y;
    const int t = threadIdx.x;
    const float* __restrict__ Z  = task ? Zt : Zr;
    const float* __restrict__ Bk = task ? Bt : Br;

    __shared__ __align__(16) float zrow[DD];
    __shared__ int sel[CAND];
    __shared__ double dsum[CAND];
    __shared__ double sval[KK];
    __shared__ int sidx[KK];
    __shared__ float sv[CAND];

    if (t < DD) zrow[t] = Z[(size_t)row * DD + t];
    sel[t] = (int)candU16[((size_t)task * BB + row) * CAND + t];
    __syncthreads();

    if (task == 0) {
        // ---- cos: exact fp64 rescore (8-lane shfl butterfly, no LDS conflicts) ----
        #pragma unroll
        for (int it = 0; it < 8; it++) {
            const int idx = t + it * 256;
            const int cnd = idx >> 3, part = idx & 7;
            const int n = sel[cnd];
            const float* brow = Bk + (size_t)n * DD + part * 16;
            double dp = 0.0;
            #pragma unroll
            for (int q = 0; q < 4; q++) {
                float4 b4 = *reinterpret_cast<const float4*>(brow + q * 4);
                const int k = part * 16 + q * 4;
                dp += (double)zrow[k + 0] * (double)b4.x + (double)zrow[k + 1] * (double)b4.y
                    + (double)zrow[k + 2] * (double)b4.z + (double)zrow[k + 3] * (double)b4.w;
            }
            dp += __shfl_xor(dp, 1, 64);
            dp += __shfl_xor(dp, 2, 64);
            dp += __shfl_xor(dp, 4, 64);
            if ((t & 7) == 0) dsum[cnd] = dp;
        }
        __syncthreads();

        if (t < 64) {
            double zq = (double)zrow[t] * (double)zrow[t]
                      + (double)zrow[t + 64] * (double)zrow[t + 64];
            #pragma unroll
            for (int m = 1; m < 64; m <<= 1) zq += __shfl_xor(zq, m, 64);

            double s[4]; int ix[4];
            #pragma unroll
            for (int j = 0; j < 4; j++) {
                const int c = t + 64 * j;
                s[j] = dsum[c]; ix[j] = sel[c];
            }

            for (int rd = 0; rd < KK; rd++) {
                double bs = s[0]; int bn = ix[0];
                #pragma unroll
                for (int j = 1; j < 4; j++)
                    if (s[j] > bs || (s[j] == bs && ix[j] < bn)) { bs = s[j]; bn = ix[j]; }
                #pragma unroll
                for (int m = 1; m < 64; m <<= 1) {
                    double os = __shfl_xor(bs, m, 64);
                    int on = __shfl_xor(bn, m, 64);
                    if (os > bs || (os == bs && on < bn)) { bs = os; bn = on; }
                }
                #pragma unroll
                for (int j = 0; j < 4; j++) if (ix[j] == bn) s[j] = -DBL_MAX;  // pop (n unique)
                if (t == 0) { sval[rd] = bs; sidx[rd] = bn; }
            }
            if (t == 0) dsum[0] = zq;
        }
        __syncthreads();

        if (t < KK) {
            const double zq = dsum[0];
            const int n = sidx[t];
            const int o = row * KK + t;
            out[O_VC + o] = (float)(sval[t] / sqrt(zq));
            out[O_IC + o] = (float)n;
            out[O_LR + o] = rotB[n];
        }
    } else {
        // ---- euc: bit-exact numpy-fp32 emulation (verified R3) ----
        {
            const int n = sel[t];
            const float* brow = Bk + (size_t)n * DD;
            float L[4], r[8], q[8];
            #pragma unroll
            for (int u = 0; u < 4; u++) L[u] = 0.f;
            #pragma unroll
            for (int u = 0; u < 8; u++) { r[u] = 0.f; q[u] = 0.f; }
            #pragma unroll
            for (int c4 = 0; c4 < 32; c4++) {
                float4 b4 = *reinterpret_cast<const float4*>(brow + c4 * 4);
                float4 z4 = *reinterpret_cast<const float4*>(&zrow[c4 * 4]);
                const int m8 = (c4 & 1) * 4;
                L[0] = __fadd_rn(L[0], __fmul_rn(z4.x, b4.x));
                L[1] = __fadd_rn(L[1], __fmul_rn(z4.y, b4.y));
                L[2] = __fadd_rn(L[2], __fmul_rn(z4.z, b4.z));
                L[3] = __fadd_rn(L[3], __fmul_rn(z4.w, b4.w));
                r[m8 + 0] = __fadd_rn(r[m8 + 0], __fmul_rn(b4.x, b4.x));
                r[m8 + 1] = __fadd_rn(r[m8 + 1], __fmul_rn(b4.y, b4.y));
                r[m8 + 2] = __fadd_rn(r[m8 + 2], __fmul_rn(b4.z, b4.z));
                r[m8 + 3] = __fadd_rn(r[m8 + 3], __fmul_rn(b4.w, b4.w));
                q[m8 + 0] = __fadd_rn(q[m8 + 0], __fmul_rn(z4.x, z4.x));
                q[m8 + 1] = __fadd_rn(q[m8 + 1], __fmul_rn(z4.y, z4.y));
                q[m8 + 2] = __fadd_rn(q[m8 + 2], __fmul_rn(z4.z, z4.z));
                q[m8 + 3] = __fadd_rn(q[m8 + 3], __fmul_rn(z4.w, z4.w));
            }
            const float dot = __fadd_rn(__fadd_rn(L[0], L[2]), __fadd_rn(L[1], L[3]));
            const float bqv = __fadd_rn(__fadd_rn(__fadd_rn(r[0], r[1]), __fadd_rn(r[2], r[3])),
                                        __fadd_rn(__fadd_rn(r[4], r[5]), __fadd_rn(r[6], r[7])));
            const float zqv = __fadd_rn(__fadd_rn(__fadd_rn(q[0], q[1]), __fadd_rn(q[2], q[3])),
                                        __fadd_rn(__fadd_rn(q[4], q[5]), __fadd_rn(q[6], q[7])));
            sv[t] = __fsub_rn(__fsub_rn(__fmul_rn(2.0f, dot), zqv), bqv);
        }
        __syncthreads();

        if (t < 64) {
            float s[4]; int ix[4];
            #pragma unroll
            for (int j = 0; j < 4; j++) { s[j] = sv[t + 64 * j]; ix[j] = sel[t + 64 * j]; }

            for (int rd = 0; rd < KK; rd++) {
                float bs = s[0]; int bn = ix[0];
                #pragma unroll
                for (int j = 1; j < 4; j++)
                    if (s[j] > bs || (s[j] == bs && ix[j] < bn)) { bs = s[j]; bn = ix[j]; }
                #pragma unroll
                for (int m = 1; m < 64; m <<= 1) {
                    float os = __shfl_xor(bs, m, 64);
                    int on = __shfl_xor(bn, m, 64);
                    if (os > bs || (os == bs && on < bn)) { bs = os; bn = on; }
                }
                #pragma unroll
                for (int j = 0; j < 4; j++) if (ix[j] == bn) s[j] = -FLT_MAX;
                if (t == 0) {
                    const int o = row * KK + rd;
                    out[O_VE + o] = bs;
                    out[O_IE + o] = (float)bn;
                    const int o3 = O_LT + o * 3;
                    out[o3 + 0] = transB[bn * 3 + 0];
                    out[o3 + 1] = transB[bn * 3 + 1];
                    out[o3 + 2] = transB[bn * 3 + 2];
                }
            }
        }
    }
}

// ---------------- launch ------------------------------------------------------------
extern "C" void kernel_launch(void* const* d_in, const int* in_sizes, int n_in,
                              void* d_out, int out_size, void* d_ws, size_t ws_size,
                              hipStream_t stream) {
    const float* zR = (const float*)d_in[0];
    const float* zT = (const float*)d_in[1];
    const float* bR = (const float*)d_in[2];
    const float* bT = (const float*)d_in[3];
    const float* rotB = (const float*)d_in[4];
    const float* transB = (const float*)d_in[5];
    float* out = (float*)d_out;

    char* ws = (char*)d_ws;
    unsigned int* Bbf = (unsigned int*)(ws + WS_BBF);
    unsigned int* bq2 = (unsigned int*)(ws + WS_BQ2);
    uint4* candU = (uint4*)(ws + WS_CAND);

    k_cvt2<<<dim3(NTILE, NSLICE, 2), 256, 0, stream>>>(bR, bT, Bbf, bq2);
    k1_sel<<<dim3(NSLICE, 64, 2), 256, 0, stream>>>(zR, zT, Bbf, bq2, candU);
    k2_final<<<dim3(BB, 2), 256, 0, stream>>>(zR, zT, bR, bT, rotB, transB,
                                              (const unsigned short*)candU, out);
}

// Round 3
// 369.129 us; speedup vs baseline: 1.2096x; 1.0049x over previous
//
#include <hip/hip_runtime.h>
#include <cfloat>
#include <climits>
#include <math.h>

// Problem constants
#define BB 2048
#define NN 50000
#define DD 128
#define KK 20

// K1 selection geometry
#define NSLICE 16
#define NSL 3125          // NN / NSLICE (exact)
#define NTILE 98          // ceil(NSL/32); tile 97 partial (21 valid entries)
#define TAILV 21          // NSL - (NTILE-1)*32 valid entries in last tile
#define LK 8              // per-lane sorted key slots
#define SLC 16            // per (row,slice) stored candidates (2 lanes x LK)
#define CAND 256          // NSLICE * SLC per row per task
#define K1W 4             // waves per k1 block (tile-split, LDS-merged)

// out layout (floats): vals_cos, ind_cos, labels_rot, vals_euc, ind_euc, labels_trans
#define O_VC 0
#define O_IC 40960
#define O_LR 81920
#define O_VE 122880
#define O_IE 163840
#define O_LT 204800

// ws layout (bytes): Bbf (fragment-ordered, padded) 25.69MB | bq2 200KB | candU 2.1MB
#define WS_BBF   0
#define WS_BQ2   25690112
#define WS_CAND  25890112

typedef short v8s __attribute__((ext_vector_type(8)));
typedef float v16f __attribute__((ext_vector_type(16)));

union U4V8 { uint4 u; v8s v; };

__device__ __forceinline__ unsigned int bf16rne(float f) {
    unsigned int x = __float_as_uint(f);
    return (x + 0x7FFFu + ((x >> 16) & 1u)) >> 16;
}
// monotone fp32 -> u32 (total order)
__device__ __forceinline__ unsigned int sortkey(float s) {
    unsigned int b = __float_as_uint(s);
    return b ^ ((unsigned int)((int)b >> 31) | 0x80000000u);
}

// compare-exchange: a=min, b=max (2 independent ops, 1-level depth)
__device__ __forceinline__ void ce(unsigned int &a, unsigned int &b) {
    unsigned int lo = min(a, b);
    unsigned int hi = max(a, b);
    a = lo; b = hi;
}
// Batcher odd-even mergesort-8, ascending (19 CEs, depth 6, high ILP)
__device__ __forceinline__ void sort8(unsigned int* k) {
    ce(k[0],k[1]); ce(k[2],k[3]); ce(k[4],k[5]); ce(k[6],k[7]);
    ce(k[0],k[2]); ce(k[1],k[3]); ce(k[4],k[6]); ce(k[5],k[7]);
    ce(k[1],k[2]); ce(k[5],k[6]);
    ce(k[0],k[4]); ce(k[1],k[5]); ce(k[2],k[6]); ce(k[3],k[7]);
    ce(k[2],k[4]); ce(k[3],k[5]);
    ce(k[1],k[2]); ce(k[3],k[4]); ce(k[5],k[6]);
}
// run asc, s asc -> run = top-8 of (run ∪ s), ascending.
// m[i] = max(run[i], s[7-i]) holds the top-8 multiset and is bitonic (valley);
// a 12-CE bitonic merge restores ascending order. Depth 4.
__device__ __forceinline__ void merge8(unsigned int (&run)[LK], const unsigned int* s) {
    unsigned int m[8];
    #pragma unroll
    for (int i = 0; i < 8; i++) m[i] = max(run[i], s[7 - i]);
    ce(m[0],m[4]); ce(m[1],m[5]); ce(m[2],m[6]); ce(m[3],m[7]);
    ce(m[0],m[2]); ce(m[1],m[3]); ce(m[4],m[6]); ce(m[5],m[7]);
    ce(m[0],m[1]); ce(m[2],m[3]); ce(m[4],m[5]); ce(m[6],m[7]);
    #pragma unroll
    for (int i = 0; i < 8; i++) run[i] = m[i];
}

// ---------------- K0: build bf16 book in MFMA-FRAGMENT ORDER + packed -bq ----------
// Layout per (task,slice,tile): 8KB tile; chunk (q,h,c) = bf16(b[e][16q+8h .. +8])*sc
// at byte offset q*1024 + h*512 + c*16, where e = slice*NSL + min(32*tile+c, NSL-1)
// (tail tile duplicates the last entry -- K1 masks those scores).
__global__ __launch_bounds__(256) void k_cvt2(const float* __restrict__ bR,
                                              const float* __restrict__ bT,
                                              unsigned int* __restrict__ Bbf,
                                              unsigned int* __restrict__ bq2)
{
    const int tile  = blockIdx.x;   // 0..97
    const int slice = blockIdx.y;   // 0..15
    const int task  = blockIdx.z;
    const int t = threadIdx.x;
    const float* __restrict__ src = task ? bT : bR;
    const float sc = task ? 2.f : 1.f;

    __shared__ float ps[4][64];

    unsigned int* tb = Bbf + (((size_t)(task * NSLICE + slice) * NTILE + tile) << 11);

    float partial = 0.f;
    #pragma unroll
    for (int half = 0; half < 2; half++) {
        const int x = t + half * 256;
        const int c = x & 31, hh = (x >> 5) & 1, q = x >> 6;
        const int es = slice * NSL + min(tile * 32 + c, NSL - 1);
        const float* p = src + (size_t)es * DD + q * 16 + hh * 8;
        float4 u0 = *reinterpret_cast<const float4*>(p);
        float4 u1 = *reinterpret_cast<const float4*>(p + 4);
        partial += u0.x * u0.x + u0.y * u0.y + u0.z * u0.z + u0.w * u0.w
                 + u1.x * u1.x + u1.y * u1.y + u1.z * u1.z + u1.w * u1.w;
        uint4 o;
        o.x = bf16rne(u0.x * sc) | (bf16rne(u0.y * sc) << 16);
        o.y = bf16rne(u0.z * sc) | (bf16rne(u0.w * sc) << 16);
        o.z = bf16rne(u1.x * sc) | (bf16rne(u1.y * sc) << 16);
        o.w = bf16rne(u1.z * sc) | (bf16rne(u1.w * sc) << 16);
        *reinterpret_cast<uint4*>(tb + (q << 8) + hh * 128 + c * 4) = o;
    }

    if (task) {
        ps[t >> 6][t & 63] = partial;
        __syncthreads();
        if (t < 32) {
            float sq = 0.f;
            #pragma unroll
            for (int w2 = 0; w2 < 4; w2++) sq += ps[w2][t] + ps[w2][t + 32];
            unsigned int hi = bf16rne(sq);
            float fhi = __uint_as_float(hi << 16);
            unsigned int lo = bf16rne(sq - fhi);
            const int e = slice * NSL + min(tile * 32 + t, NSL - 1);
            bq2[e] = (hi ^ 0x8000u) | ((lo ^ 0x8000u) << 16);  // packed (-bq_hi, -bq_lo)
        }
    }
}

// ---------------- K1: swapped-operand MFMA scoring + Batcher-network top-8 ----------
// K1W waves per (slice, rowgroup-of-32, task); wave w handles tiles w, w+K1W, ...
// Per tile: 16 keys -> two sort8 (19 CE each) -> two bitonic top-8 merges into the
// running ascending list. Exact top-8 multiset per lane (keys unique), so candU is
// bit-identical to the serial-insert version, but dependency depth per tile drops
// ~512cy -> ~100cy (the R2 bottleneck: VALUBusy 51% with idle dep-stall).
__global__ __launch_bounds__(256, 4) void k1_sel(
    const float* __restrict__ zR, const float* __restrict__ zT,
    const unsigned int* __restrict__ Bbf,
    const unsigned int* __restrict__ bq2,
    uint4* __restrict__ candU)
{
    const int slice = blockIdx.x;       // 0..15
    const int rg    = blockIdx.y;       // 0..63
    const int task  = blockIdx.z;
    const int w     = threadIdx.x >> 6; // wave 0..3
    const int lane  = threadIdx.x & 63;
    const int col   = lane & 31;
    const int h     = lane >> 5;

    __shared__ unsigned int smk[K1W - 1][64][LK + 1];   // stride-9 pad: conflict-free

    // ---- persistent z-frags (B operand): row = rg*32+col, k = 16q+8h..+8 ----
    const float* zp = (task ? zT : zR) + (size_t)(rg * 32 + col) * DD;
    v8s zf[9];
    #pragma unroll
    for (int q = 0; q < 8; q++) {
        float4 u0 = *reinterpret_cast<const float4*>(zp + q * 16 + h * 8);
        float4 u1 = *reinterpret_cast<const float4*>(zp + q * 16 + h * 8 + 4);
        U4V8 c;
        c.u.x = bf16rne(u0.x) | (bf16rne(u0.y) << 16);
        c.u.y = bf16rne(u0.z) | (bf16rne(u0.w) << 16);
        c.u.z = bf16rne(u1.x) | (bf16rne(u1.y) << 16);
        c.u.w = bf16rne(u1.z) | (bf16rne(u1.w) << 16);
        zf[q] = c.v;
    }
    {   // 9th step: k=128,129 -> 1.0,1.0 (h=0); zeros (h=1)
        U4V8 c; c.u = make_uint4(h == 0 ? 0x3F803F80u : 0u, 0u, 0u, 0u);
        zf[8] = c.v;
    }

    unsigned int run[LK];
    #pragma unroll
    for (int u = 0; u < LK; u++) run[u] = 0u;

    const int nbase0 = slice * NSL;
    const unsigned int* bp = Bbf + ((size_t)(task * NSLICE + slice) * NTILE << 11) + lane * 4;

#define TILE_BODY(TILE, TAIL)                                                          \
    {                                                                                  \
        const unsigned int* tb = bp + ((size_t)(TILE) << 11);                          \
        v16f acc = {0.f,0.f,0.f,0.f, 0.f,0.f,0.f,0.f,                                  \
                    0.f,0.f,0.f,0.f, 0.f,0.f,0.f,0.f};                                 \
        _Pragma("unroll")                                                              \
        for (int q = 0; q < 8; q++) {                                                  \
            U4V8 a; a.u = *reinterpret_cast<const uint4*>(tb + (q << 8));              \
            acc = __builtin_amdgcn_mfma_f32_32x32x16_bf16(a.v, zf[q], acc, 0, 0, 0);   \
        }                                                                              \
        if (task) {                                                                    \
            int e = nbase0 + (TILE) * 32 + col;                                        \
            if (TAIL) e = min(e, nbase0 + NSL - 1);                                    \
            unsigned int bqp = bq2[e];                                                 \
            U4V8 a; a.u = make_uint4(h == 0 ? bqp : 0u, 0u, 0u, 0u);                   \
            acc = __builtin_amdgcn_mfma_f32_32x32x16_bf16(a.v, zf[8], acc, 0, 0, 0);   \
        }                                                                              \
        const int nb = nbase0 + (TILE) * 32 + 4 * h;                                   \
        unsigned int kk[16];                                                           \
        _Pragma("unroll")                                                              \
        for (int r = 0; r < 16; r++) {                                                 \
            const int pat = (r & 3) + 8 * (r >> 2);                                    \
            const int n = nb + pat;                                                    \
            unsigned int k = (sortkey(acc[r]) & 0xFFFF0000u) | (unsigned int)n;        \
            if (TAIL && (pat + 4 * h >= TAILV)) k = 0u;                                \
            kk[r] = k;                                                                 \
        }                                                                              \
        sort8(&kk[0]); sort8(&kk[8]);                                                  \
        merge8(run, &kk[0]); merge8(run, &kk[8]);                                      \
    }

    int tile = w;
    for (; tile < NTILE - 1; tile += K1W) TILE_BODY(tile, 0)
    if (tile == NTILE - 1) TILE_BODY(tile, 1)
#undef TILE_BODY

    // ---- cross-wave merge: waves 1..3 publish sorted-8, wave 0 does 3 merge8 ----
    if (w > 0) {
        #pragma unroll
        for (int u = 0; u < LK; u++) smk[w - 1][lane][u] = run[u];
    }
    __syncthreads();
    if (w == 0) {
        #pragma unroll
        for (int v = 0; v < K1W - 1; v++) {
            unsigned int s[LK];
            #pragma unroll
            for (int u = 0; u < LK; u++) s[u] = smk[v][lane][u];
            merge8(run, s);
        }

        // ---- writeout: 8 entry-indices per lane -> 16B store; 16 per (row,slice) ----
        uint4 o;
        o.x = (run[0] & 0xFFFFu) | ((run[1] & 0xFFFFu) << 16);
        o.y = (run[2] & 0xFFFFu) | ((run[3] & 0xFFFFu) << 16);
        o.z = (run[4] & 0xFFFFu) | ((run[5] & 0xFFFFu) << 16);
        o.w = (run[6] & 0xFFFFu) | ((run[7] & 0xFFFFu) << 16);
        const int row = rg * 32 + col;
        candU[((size_t)(task * BB + row) * NSLICE + slice) * 2 + h] = o;
    }
}

// ---------------- K2: exact final ranking + gather (unchanged this round) ----------
__global__ __launch_bounds__(256) void k2_final(
    const float* __restrict__ Zr, const float* __restrict__ Zt,
    const float* __restrict__ Br, const float* __restrict__ Bt,
    const float* __restrict__ rotB, const float* __restrict__ transB,
    const unsigned short* __restrict__ candU16,
    float* __restrict__ out)
{
    const int row = blockIdx.x;
    const int task = blockIdx.y;
    const int t = threadIdx.x;
    const float* __restrict__ Z  = task ? Zt : Zr;
    const float* __restrict__ Bk = task ? Bt : Br;

    __shared__ __align__(16) float zrow[DD];
    __shared__ int sel[CAND];
    __shared__ double dsum[CAND];
    __shared__ double sval[KK];
    __shared__ int sidx[KK];
    __shared__ float sv[CAND];

    if (t < DD) zrow[t] = Z[(size_t)row * DD + t];
    sel[t] = (int)candU16[((size_t)task * BB + row) * CAND + t];
    __syncthreads();

    if (task == 0) {
        // ---- cos: exact fp64 rescore (8-lane shfl butterfly, no LDS conflicts) ----
        #pragma unroll
        for (int it = 0; it < 8; it++) {
            const int idx = t + it * 256;
            const int cnd = idx >> 3, part = idx & 7;
            const int n = sel[cnd];
            const float* brow = Bk + (size_t)n * DD + part * 16;
            double dp = 0.0;
            #pragma unroll
            for (int q = 0; q < 4; q++) {
                float4 b4 = *reinterpret_cast<const float4*>(brow + q * 4);
                const int k = part * 16 + q * 4;
                dp += (double)zrow[k + 0] * (double)b4.x + (double)zrow[k + 1] * (double)b4.y
                    + (double)zrow[k + 2] * (double)b4.z + (double)zrow[k + 3] * (double)b4.w;
            }
            dp += __shfl_xor(dp, 1, 64);
            dp += __shfl_xor(dp, 2, 64);
            dp += __shfl_xor(dp, 4, 64);
            if ((t & 7) == 0) dsum[cnd] = dp;
        }
        __syncthreads();

        if (t < 64) {
            double zq = (double)zrow[t] * (double)zrow[t]
                      + (double)zrow[t + 64] * (double)zrow[t + 64];
            #pragma unroll
            for (int m = 1; m < 64; m <<= 1) zq += __shfl_xor(zq, m, 64);

            double s[4]; int ix[4];
            #pragma unroll
            for (int j = 0; j < 4; j++) {
                const int c = t + 64 * j;
                s[j] = dsum[c]; ix[j] = sel[c];
            }

            for (int rd = 0; rd < KK; rd++) {
                double bs = s[0]; int bn = ix[0];
                #pragma unroll
                for (int j = 1; j < 4; j++)
                    if (s[j] > bs || (s[j] == bs && ix[j] < bn)) { bs = s[j]; bn = ix[j]; }
                #pragma unroll
                for (int m = 1; m < 64; m <<= 1) {
                    double os = __shfl_xor(bs, m, 64);
                    int on = __shfl_xor(bn, m, 64);
                    if (os > bs || (os == bs && on < bn)) { bs = os; bn = on; }
                }
                #pragma unroll
                for (int j = 0; j < 4; j++) if (ix[j] == bn) s[j] = -DBL_MAX;
                if (t == 0) { sval[rd] = bs; sidx[rd] = bn; }
            }
            if (t == 0) dsum[0] = zq;
        }
        __syncthreads();

        if (t < KK) {
            const double zq = dsum[0];
            const int n = sidx[t];
            const int o = row * KK + t;
            out[O_VC + o] = (float)(sval[t] / sqrt(zq));
            out[O_IC + o] = (float)n;
            out[O_LR + o] = rotB[n];
        }
    } else {
        // ---- euc: bit-exact numpy-fp32 emulation ----
        {
            const int n = sel[t];
            const float* brow = Bk + (size_t)n * DD;
            float L[4], r[8], q[8];
            #pragma unroll
            for (int u = 0; u < 4; u++) L[u] = 0.f;
            #pragma unroll
            for (int u = 0; u < 8; u++) { r[u] = 0.f; q[u] = 0.f; }
            #pragma unroll
            for (int c4 = 0; c4 < 32; c4++) {
                float4 b4 = *reinterpret_cast<const float4*>(brow + c4 * 4);
                float4 z4 = *reinterpret_cast<const float4*>(&zrow[c4 * 4]);
                const int m8 = (c4 & 1) * 4;
                L[0] = __fadd_rn(L[0], __fmul_rn(z4.x, b4.x));
                L[1] = __fadd_rn(L[1], __fmul_rn(z4.y, b4.y));
                L[2] = __fadd_rn(L[2], __fmul_rn(z4.z, b4.z));
                L[3] = __fadd_rn(L[3], __fmul_rn(z4.w, b4.w));
                r[m8 + 0] = __fadd_rn(r[m8 + 0], __fmul_rn(b4.x, b4.x));
                r[m8 + 1] = __fadd_rn(r[m8 + 1], __fmul_rn(b4.y, b4.y));
                r[m8 + 2] = __fadd_rn(r[m8 + 2], __fmul_rn(b4.z, b4.z));
                r[m8 + 3] = __fadd_rn(r[m8 + 3], __fmul_rn(b4.w, b4.w));
                q[m8 + 0] = __fadd_rn(q[m8 + 0], __fmul_rn(z4.x, z4.x));
                q[m8 + 1] = __fadd_rn(q[m8 + 1], __fmul_rn(z4.y, z4.y));
                q[m8 + 2] = __fadd_rn(q[m8 + 2], __fmul_rn(z4.z, z4.z));
                q[m8 + 3] = __fadd_rn(q[m8 + 3], __fmul_rn(z4.w, z4.w));
            }
            const float dot = __fadd_rn(__fadd_rn(L[0], L[2]), __fadd_rn(L[1], L[3]));
            const float bqv = __fadd_rn(__fadd_rn(__fadd_rn(r[0], r[1]), __fadd_rn(r[2], r[3])),
                                        __fadd_rn(__fadd_rn(r[4], r[5]), __fadd_rn(r[6], r[7])));
            const float zqv = __fadd_rn(__fadd_rn(__fadd_rn(q[0], q[1]), __fadd_rn(q[2], q[3])),
                                        __fadd_rn(__fadd_rn(q[4], q[5]), __fadd_rn(q[6], q[7])));
            sv[t] = __fsub_rn(__fsub_rn(__fmul_rn(2.0f, dot), zqv), bqv);
        }
        __syncthreads();

        if (t < 64) {
            float s[4]; int ix[4];
            #pragma unroll
            for (int j = 0; j < 4; j++) { s[j] = sv[t + 64 * j]; ix[j] = sel[t + 64 * j]; }

            for (int rd = 0; rd < KK; rd++) {
                float bs = s[0]; int bn = ix[0];
                #pragma unroll
                for (int j = 1; j < 4; j++)
                    if (s[j] > bs || (s[j] == bs && ix[j] < bn)) { bs = s[j]; bn = ix[j]; }
                #pragma unroll
                for (int m = 1; m < 64; m <<= 1) {
                    float os = __shfl_xor(bs, m, 64);
                    int on = __shfl_xor(bn, m, 64);
                    if (os > bs || (os == bs && on < bn)) { bs = os; bn = on; }
                }
                #pragma unroll
                for (int j = 0; j < 4; j++) if (ix[j] == bn) s[j] = -FLT_MAX;
                if (t == 0) {
                    const int o = row * KK + rd;
                    out[O_VE + o] = bs;
                    out[O_IE + o] = (float)bn;
                    const int o3 = O_LT + o * 3;
                    out[o3 + 0] = transB[bn * 3 + 0];
                    out[o3 + 1] = transB[bn * 3 + 1];
                    out[o3 + 2] = transB[bn * 3 + 2];
                }
            }
        }
    }
}

// ---------------- launch ------------------------------------------------------------
extern "C" void kernel_launch(void* const* d_in, const int* in_sizes, int n_in,
                              void* d_out, int out_size, void* d_ws, size_t ws_size,
                              hipStream_t stream) {
    const float* zR = (const float*)d_in[0];
    const float* zT = (const float*)d_in[1];
    const float* bR = (const float*)d_in[2];
    const float* bT = (const float*)d_in[3];
    const float* rotB = (const float*)d_in[4];
    const float* transB = (const float*)d_in[5];
    float* out = (float*)d_out;

    char* ws = (char*)d_ws;
    unsigned int* Bbf = (unsigned int*)(ws + WS_BBF);
    unsigned int* bq2 = (unsigned int*)(ws + WS_BQ2);
    uint4* candU = (uint4*)(ws + WS_CAND);

    k_cvt2<<<dim3(NTILE, NSLICE, 2), 256, 0, stream>>>(bR, bT, Bbf, bq2);
    k1_sel<<<dim3(NSLICE, 64, 2), 256, 0, stream>>>(zR, zT, Bbf, bq2, candU);
    k2_final<<<dim3(BB, 2), 256, 0, stream>>>(zR, zT, bR, bT, rotB, transB,
                                              (const unsigned short*)candU, out);
}

// Round 4
// 343.788 us; speedup vs baseline: 1.2988x; 1.0737x over previous
//
#include <hip/hip_runtime.h>
#include <cfloat>
#include <climits>
#include <math.h>

// Problem constants
#define BB 2048
#define NN 50000
#define DD 128
#define KK 20

// K1 selection geometry
#define NSLICE 16
#define NSL 3125          // NN / NSLICE (exact)
#define NTILE 98          // ceil(NSL/32); tile 97 partial (21 valid entries)
#define TAILV 21          // NSL - (NTILE-1)*32 valid entries in last tile
#define LK 8              // per-lane sorted key slots
#define SLC 16            // per (row,slice) stored candidates (2 lanes x LK)
#define CAND 256          // NSLICE * SLC per row per task
#define K1W 4             // waves per k1 block (tile-split, LDS-merged)

// out layout (floats): vals_cos, ind_cos, labels_rot, vals_euc, ind_euc, labels_trans
#define O_VC 0
#define O_IC 40960
#define O_LR 81920
#define O_VE 122880
#define O_IE 163840
#define O_LT 204800

// ws layout (bytes): Bbf (fragment-ordered, padded) 25.69MB | bq2 200KB | candU 2.1MB
#define WS_BBF   0
#define WS_BQ2   25690112
#define WS_CAND  25890112

typedef short v8s __attribute__((ext_vector_type(8)));
typedef float v16f __attribute__((ext_vector_type(16)));

union U4V8 { uint4 u; v8s v; };

__device__ __forceinline__ unsigned int bf16rne(float f) {
    unsigned int x = __float_as_uint(f);
    return (x + 0x7FFFu + ((x >> 16) & 1u)) >> 16;
}
// monotone fp32 -> u32 (total order)
__device__ __forceinline__ unsigned int sortkey(float s) {
    unsigned int b = __float_as_uint(s);
    return b ^ ((unsigned int)((int)b >> 31) | 0x80000000u);
}
// single-instruction sorted-insert step: med3(k, key[u], key[u+1]) ==
// min(key[u+1], max(k, key[u])) under the sortedness invariant key[u] <= key[u+1]
__device__ __forceinline__ unsigned int med3u(unsigned int a, unsigned int b, unsigned int c) {
    unsigned int d;
    asm("v_med3_u32 %0, %1, %2, %3" : "=v"(d) : "v"(a), "v"(b), "v"(c));
    return d;
}
// low-register-pressure top-8 insert (consumes one key at a time; run ascending)
__device__ __forceinline__ void ins8(unsigned int (&run)[LK], unsigned int k) {
    #pragma unroll
    for (int u = 0; u < LK - 1; u++) run[u] = med3u(k, run[u], run[u + 1]);
    run[LK - 1] = max(k, run[LK - 1]);
}
// compare-exchange (for the block-merge network only)
__device__ __forceinline__ void ce(unsigned int &a, unsigned int &b) {
    unsigned int lo = min(a, b);
    unsigned int hi = max(a, b);
    a = lo; b = hi;
}
// run asc, s asc -> run = top-8 of (run ∪ s), ascending (8 max + 12-CE bitonic)
__device__ __forceinline__ void merge8(unsigned int (&run)[LK], const unsigned int* s) {
    unsigned int m[8];
    #pragma unroll
    for (int i = 0; i < 8; i++) m[i] = max(run[i], s[7 - i]);
    ce(m[0],m[4]); ce(m[1],m[5]); ce(m[2],m[6]); ce(m[3],m[7]);
    ce(m[0],m[2]); ce(m[1],m[3]); ce(m[4],m[6]); ce(m[5],m[7]);
    ce(m[0],m[1]); ce(m[2],m[3]); ce(m[4],m[5]); ce(m[6],m[7]);
    #pragma unroll
    for (int i = 0; i < 8; i++) run[i] = m[i];
}

// ---------------- K0: build bf16 book in MFMA-FRAGMENT ORDER + packed -bq ----------
// Layout per (task,slice,tile): 8KB tile; chunk (q,h,c) = bf16(b[e][16q+8h .. +8])*sc
// at byte offset q*1024 + h*512 + c*16, where e = slice*NSL + min(32*tile+c, NSL-1)
// (tail tile duplicates the last entry -- K1 masks those scores).
__global__ __launch_bounds__(256) void k_cvt2(const float* __restrict__ bR,
                                              const float* __restrict__ bT,
                                              unsigned int* __restrict__ Bbf,
                                              unsigned int* __restrict__ bq2)
{
    const int tile  = blockIdx.x;   // 0..97
    const int slice = blockIdx.y;   // 0..15
    const int task  = blockIdx.z;
    const int t = threadIdx.x;
    const float* __restrict__ src = task ? bT : bR;
    const float sc = task ? 2.f : 1.f;

    __shared__ float ps[4][64];

    unsigned int* tb = Bbf + (((size_t)(task * NSLICE + slice) * NTILE + tile) << 11);

    float partial = 0.f;
    #pragma unroll
    for (int half = 0; half < 2; half++) {
        const int x = t + half * 256;
        const int c = x & 31, hh = (x >> 5) & 1, q = x >> 6;
        const int es = slice * NSL + min(tile * 32 + c, NSL - 1);
        const float* p = src + (size_t)es * DD + q * 16 + hh * 8;
        float4 u0 = *reinterpret_cast<const float4*>(p);
        float4 u1 = *reinterpret_cast<const float4*>(p + 4);
        partial += u0.x * u0.x + u0.y * u0.y + u0.z * u0.z + u0.w * u0.w
                 + u1.x * u1.x + u1.y * u1.y + u1.z * u1.z + u1.w * u1.w;
        uint4 o;
        o.x = bf16rne(u0.x * sc) | (bf16rne(u0.y * sc) << 16);
        o.y = bf16rne(u0.z * sc) | (bf16rne(u0.w * sc) << 16);
        o.z = bf16rne(u1.x * sc) | (bf16rne(u1.y * sc) << 16);
        o.w = bf16rne(u1.z * sc) | (bf16rne(u1.w * sc) << 16);
        *reinterpret_cast<uint4*>(tb + (q << 8) + hh * 128 + c * 4) = o;
    }

    if (task) {
        ps[t >> 6][t & 63] = partial;
        __syncthreads();
        if (t < 32) {
            float sq = 0.f;
            #pragma unroll
            for (int w2 = 0; w2 < 4; w2++) sq += ps[w2][t] + ps[w2][t + 32];
            unsigned int hi = bf16rne(sq);
            float fhi = __uint_as_float(hi << 16);
            unsigned int lo = bf16rne(sq - fhi);
            const int e = slice * NSL + min(tile * 32 + t, NSL - 1);
            bq2[e] = (hi ^ 0x8000u) | ((lo ^ 0x8000u) << 16);  // packed (-bq_hi, -bq_lo)
        }
    }
}

// ---------------- K1: MFMA scoring, z-frags in LDS, med3-chain top-8 ---------------
// R3 post-mortem: zf[9] (36 regs) lived in AGPRs -> unified ~92 regs/wave -> only
// ~5.5 waves/SIMD resident (measured 46% occupancy) -> 32% all-stall. Fix: the 4
// waves of a block share IDENTICAL z-frags; wave 0 writes them to LDS once and the
// hot loop ds_read_b128's the B-operand per MFMA. Unified regs ~56-64 -> 8 waves/SIMD.
// Selection = R2's verified med3 chain (lowest register pressure; issue-bound regime).
// Candidates bit-identical to R1/R2/R3.
__global__ __launch_bounds__(256, 8) void k1_sel(
    const float* __restrict__ zR, const float* __restrict__ zT,
    const unsigned int* __restrict__ Bbf,
    const unsigned int* __restrict__ bq2,
    uint4* __restrict__ candU)
{
    const int slice = blockIdx.x;       // 0..15
    const int rg    = blockIdx.y;       // 0..63
    const int task  = blockIdx.z;
    const int w     = threadIdx.x >> 6; // wave 0..3
    const int lane  = threadIdx.x & 63;
    const int col   = lane & 31;
    const int h     = lane >> 5;

    __shared__ uint4 zs[8][64];                         // 8 KB shared z-frags
    __shared__ unsigned int smk[K1W - 1][64][LK + 1];   // stride-9 pad, 6.75 KB

    // ---- wave 0 builds the shared z-frags: row = rg*32+col, k = 16q+8h..+8 ----
    if (w == 0) {
        const float* zp = (task ? zT : zR) + (size_t)(rg * 32 + col) * DD;
        #pragma unroll
        for (int q = 0; q < 8; q++) {
            float4 u0 = *reinterpret_cast<const float4*>(zp + q * 16 + h * 8);
            float4 u1 = *reinterpret_cast<const float4*>(zp + q * 16 + h * 8 + 4);
            uint4 c;
            c.x = bf16rne(u0.x) | (bf16rne(u0.y) << 16);
            c.y = bf16rne(u0.z) | (bf16rne(u0.w) << 16);
            c.z = bf16rne(u1.x) | (bf16rne(u1.y) << 16);
            c.w = bf16rne(u1.z) | (bf16rne(u1.w) << 16);
            zs[q][lane] = c;
        }
    }
    // 9th-step pseudo-frag: k=128,129 -> 1.0,1.0 (h=0); zeros (h=1) — 1 reg-pair, tiny
    U4V8 zf8; zf8.u = make_uint4(h == 0 ? 0x3F803F80u : 0u, 0u, 0u, 0u);
    __syncthreads();

    unsigned int run[LK];
    #pragma unroll
    for (int u = 0; u < LK; u++) run[u] = 0u;

    const int nbase0 = slice * NSL;
    const unsigned int* bp = Bbf + ((size_t)(task * NSLICE + slice) * NTILE << 11) + lane * 4;

#define TILE_BODY(TILE, TAIL)                                                          \
    {                                                                                  \
        asm volatile("" ::: "memory");  /* keep zs reads per-tile (no 32-reg hoist) */ \
        const unsigned int* tb = bp + ((size_t)(TILE) << 11);                          \
        v16f acc = {0.f,0.f,0.f,0.f, 0.f,0.f,0.f,0.f,                                  \
                    0.f,0.f,0.f,0.f, 0.f,0.f,0.f,0.f};                                 \
        _Pragma("unroll")                                                              \
        for (int q = 0; q < 8; q++) {                                                  \
            U4V8 a; a.u = *reinterpret_cast<const uint4*>(tb + (q << 8));              \
            U4V8 z; z.u = zs[q][lane];                                                 \
            acc = __builtin_amdgcn_mfma_f32_32x32x16_bf16(a.v, z.v, acc, 0, 0, 0);     \
        }                                                                              \
        if (task) {                                                                    \
            int e = nbase0 + (TILE) * 32 + col;                                        \
            if (TAIL) e = min(e, nbase0 + NSL - 1);                                    \
            unsigned int bqp = bq2[e];                                                 \
            U4V8 a; a.u = make_uint4(h == 0 ? bqp : 0u, 0u, 0u, 0u);                   \
            acc = __builtin_amdgcn_mfma_f32_32x32x16_bf16(a.v, zf8.v, acc, 0, 0, 0);   \
        }                                                                              \
        const int nb = nbase0 + (TILE) * 32 + 4 * h;                                   \
        _Pragma("unroll")                                                              \
        for (int r = 0; r < 16; r++) {                                                 \
            const int pat = (r & 3) + 8 * (r >> 2);                                    \
            const int n = nb + pat;                                                    \
            unsigned int k = (sortkey(acc[r]) & 0xFFFF0000u) | (unsigned int)n;        \
            if (TAIL && (pat + 4 * h >= TAILV)) k = 0u;                                \
            ins8(run, k);                                                              \
        }                                                                              \
    }

    int tile = w;
    for (; tile < NTILE - 1; tile += K1W) TILE_BODY(tile, 0)
    if (tile == NTILE - 1) TILE_BODY(tile, 1)
#undef TILE_BODY

    // ---- cross-wave merge: waves 1..3 publish sorted-8, wave 0 does 3 merge8 ----
    if (w > 0) {
        #pragma unroll
        for (int u = 0; u < LK; u++) smk[w - 1][lane][u] = run[u];
    }
    __syncthreads();
    if (w == 0) {
        #pragma unroll
        for (int v = 0; v < K1W - 1; v++) {
            unsigned int s[LK];
            #pragma unroll
            for (int u = 0; u < LK; u++) s[u] = smk[v][lane][u];
            merge8(run, s);
        }

        // ---- writeout: 8 entry-indices per lane -> 16B store; 16 per (row,slice) ----
        uint4 o;
        o.x = (run[0] & 0xFFFFu) | ((run[1] & 0xFFFFu) << 16);
        o.y = (run[2] & 0xFFFFu) | ((run[3] & 0xFFFFu) << 16);
        o.z = (run[4] & 0xFFFFu) | ((run[5] & 0xFFFFu) << 16);
        o.w = (run[6] & 0xFFFFu) | ((run[7] & 0xFFFFu) << 16);
        const int row = rg * 32 + col;
        candU[((size_t)(task * BB + row) * NSLICE + slice) * 2 + h] = o;
    }
}

// ---------------- K2: exact final ranking + gather (unchanged this round) ----------
__global__ __launch_bounds__(256) void k2_final(
    const float* __restrict__ Zr, const float* __restrict__ Zt,
    const float* __restrict__ Br, const float* __restrict__ Bt,
    const float* __restrict__ rotB, const float* __restrict__ transB,
    const unsigned short* __restrict__ candU16,
    float* __restrict__ out)
{
    const int row = blockIdx.x;
    const int task = blockIdx.y;
    const int t = threadIdx.x;
    const float* __restrict__ Z  = task ? Zt : Zr;
    const float* __restrict__ Bk = task ? Bt : Br;

    __shared__ __align__(16) float zrow[DD];
    __shared__ int sel[CAND];
    __shared__ double dsum[CAND];
    __shared__ double sval[KK];
    __shared__ int sidx[KK];
    __shared__ float sv[CAND];

    if (t < DD) zrow[t] = Z[(size_t)row * DD + t];
    sel[t] = (int)candU16[((size_t)task * BB + row) * CAND + t];
    __syncthreads();

    if (task == 0) {
        // ---- cos: exact fp64 rescore (8-lane shfl butterfly, no LDS conflicts) ----
        #pragma unroll
        for (int it = 0; it < 8; it++) {
            const int idx = t + it * 256;
            const int cnd = idx >> 3, part = idx & 7;
            const int n = sel[cnd];
            const float* brow = Bk + (size_t)n * DD + part * 16;
            double dp = 0.0;
            #pragma unroll
            for (int q = 0; q < 4; q++) {
                float4 b4 = *reinterpret_cast<const float4*>(brow + q * 4);
                const int k = part * 16 + q * 4;
                dp += (double)zrow[k + 0] * (double)b4.x + (double)zrow[k + 1] * (double)b4.y
                    + (double)zrow[k + 2] * (double)b4.z + (double)zrow[k + 3] * (double)b4.w;
            }
            dp += __shfl_xor(dp, 1, 64);
            dp += __shfl_xor(dp, 2, 64);
            dp += __shfl_xor(dp, 4, 64);
            if ((t & 7) == 0) dsum[cnd] = dp;
        }
        __syncthreads();

        if (t < 64) {
            double zq = (double)zrow[t] * (double)zrow[t]
                      + (double)zrow[t + 64] * (double)zrow[t + 64];
            #pragma unroll
            for (int m = 1; m < 64; m <<= 1) zq += __shfl_xor(zq, m, 64);

            double s[4]; int ix[4];
            #pragma unroll
            for (int j = 0; j < 4; j++) {
                const int c = t + 64 * j;
                s[j] = dsum[c]; ix[j] = sel[c];
            }

            for (int rd = 0; rd < KK; rd++) {
                double bs = s[0]; int bn = ix[0];
                #pragma unroll
                for (int j = 1; j < 4; j++)
                    if (s[j] > bs || (s[j] == bs && ix[j] < bn)) { bs = s[j]; bn = ix[j]; }
                #pragma unroll
                for (int m = 1; m < 64; m <<= 1) {
                    double os = __shfl_xor(bs, m, 64);
                    int on = __shfl_xor(bn, m, 64);
                    if (os > bs || (os == bs && on < bn)) { bs = os; bn = on; }
                }
                #pragma unroll
                for (int j = 0; j < 4; j++) if (ix[j] == bn) s[j] = -DBL_MAX;
                if (t == 0) { sval[rd] = bs; sidx[rd] = bn; }
            }
            if (t == 0) dsum[0] = zq;
        }
        __syncthreads();

        if (t < KK) {
            const double zq = dsum[0];
            const int n = sidx[t];
            const int o = row * KK + t;
            out[O_VC + o] = (float)(sval[t] / sqrt(zq));
            out[O_IC + o] = (float)n;
            out[O_LR + o] = rotB[n];
        }
    } else {
        // ---- euc: bit-exact numpy-fp32 emulation ----
        {
            const int n = sel[t];
            const float* brow = Bk + (size_t)n * DD;
            float L[4], r[8], q[8];
            #pragma unroll
            for (int u = 0; u < 4; u++) L[u] = 0.f;
            #pragma unroll
            for (int u = 0; u < 8; u++) { r[u] = 0.f; q[u] = 0.f; }
            #pragma unroll
            for (int c4 = 0; c4 < 32; c4++) {
                float4 b4 = *reinterpret_cast<const float4*>(brow + c4 * 4);
                float4 z4 = *reinterpret_cast<const float4*>(&zrow[c4 * 4]);
                const int m8 = (c4 & 1) * 4;
                L[0] = __fadd_rn(L[0], __fmul_rn(z4.x, b4.x));
                L[1] = __fadd_rn(L[1], __fmul_rn(z4.y, b4.y));
                L[2] = __fadd_rn(L[2], __fmul_rn(z4.z, b4.z));
                L[3] = __fadd_rn(L[3], __fmul_rn(z4.w, b4.w));
                r[m8 + 0] = __fadd_rn(r[m8 + 0], __fmul_rn(b4.x, b4.x));
                r[m8 + 1] = __fadd_rn(r[m8 + 1], __fmul_rn(b4.y, b4.y));
                r[m8 + 2] = __fadd_rn(r[m8 + 2], __fmul_rn(b4.z, b4.z));
                r[m8 + 3] = __fadd_rn(r[m8 + 3], __fmul_rn(b4.w, b4.w));
                q[m8 + 0] = __fadd_rn(q[m8 + 0], __fmul_rn(z4.x, z4.x));
                q[m8 + 1] = __fadd_rn(q[m8 + 1], __fmul_rn(z4.y, z4.y));
                q[m8 + 2] = __fadd_rn(q[m8 + 2], __fmul_rn(z4.z, z4.z));
                q[m8 + 3] = __fadd_rn(q[m8 + 3], __fmul_rn(z4.w, z4.w));
            }
            const float dot = __fadd_rn(__fadd_rn(L[0], L[2]), __fadd_rn(L[1], L[3]));
            const float bqv = __fadd_rn(__fadd_rn(__fadd_rn(r[0], r[1]), __fadd_rn(r[2], r[3])),
                                        __fadd_rn(__fadd_rn(r[4], r[5]), __fadd_rn(r[6], r[7])));
            const float zqv = __fadd_rn(__fadd_rn(__fadd_rn(q[0], q[1]), __fadd_rn(q[2], q[3])),
                                        __fadd_rn(__fadd_rn(q[4], q[5]), __fadd_rn(q[6], q[7])));
            sv[t] = __fsub_rn(__fsub_rn(__fmul_rn(2.0f, dot), zqv), bqv);
        }
        __syncthreads();

        if (t < 64) {
            float s[4]; int ix[4];
            #pragma unroll
            for (int j = 0; j < 4; j++) { s[j] = sv[t + 64 * j]; ix[j] = sel[t + 64 * j]; }

            for (int rd = 0; rd < KK; rd++) {
                float bs = s[0]; int bn = ix[0];
                #pragma unroll
                for (int j = 1; j < 4; j++)
                    if (s[j] > bs || (s[j] == bs && ix[j] < bn)) { bs = s[j]; bn = ix[j]; }
                #pragma unroll
                for (int m = 1; m < 64; m <<= 1) {
                    float os = __shfl_xor(bs, m, 64);
                    int on = __shfl_xor(bn, m, 64);
                    if (os > bs || (os == bs && on < bn)) { bs = os; bn = on; }
                }
                #pragma unroll
                for (int j = 0; j < 4; j++) if (ix[j] == bn) s[j] = -FLT_MAX;
                if (t == 0) {
                    const int o = row * KK + rd;
                    out[O_VE + o] = bs;
                    out[O_IE + o] = (float)bn;
                    const int o3 = O_LT + o * 3;
                    out[o3 + 0] = transB[bn * 3 + 0];
                    out[o3 + 1] = transB[bn * 3 + 1];
                    out[o3 + 2] = transB[bn * 3 + 2];
                }
            }
        }
    }
}

// ---------------- launch ------------------------------------------------------------
extern "C" void kernel_launch(void* const* d_in, const int* in_sizes, int n_in,
                              void* d_out, int out_size, void* d_ws, size_t ws_size,
                              hipStream_t stream) {
    const float* zR = (const float*)d_in[0];
    const float* zT = (const float*)d_in[1];
    const float* bR = (const float*)d_in[2];
    const float* bT = (const float*)d_in[3];
    const float* rotB = (const float*)d_in[4];
    const float* transB = (const float*)d_in[5];
    float* out = (float*)d_out;

    char* ws = (char*)d_ws;
    unsigned int* Bbf = (unsigned int*)(ws + WS_BBF);
    unsigned int* bq2 = (unsigned int*)(ws + WS_BQ2);
    uint4* candU = (uint4*)(ws + WS_CAND);

    k_cvt2<<<dim3(NTILE, NSLICE, 2), 256, 0, stream>>>(bR, bT, Bbf, bq2);
    k1_sel<<<dim3(NSLICE, 64, 2), 256, 0, stream>>>(zR, zT, Bbf, bq2, candU);
    k2_final<<<dim3(BB, 2), 256, 0, stream>>>(zR, zT, bR, bT, rotB, transB,
                                              (const unsigned short*)candU, out);
}

// Round 6
// 335.442 us; speedup vs baseline: 1.3311x; 1.0249x over previous
//
#include <hip/hip_runtime.h>
#include <cfloat>
#include <climits>
#include <math.h>

// Problem constants
#define BB 2048
#define NN 50000
#define DD 128
#define KK 20

// K1 selection geometry
#define NSLICE 16
#define NSL 3125          // NN / NSLICE (exact)
#define NTILE 98          // ceil(NSL/32); tile 97 partial (21 valid entries)
#define TAILV 21          // NSL - (NTILE-1)*32 valid entries in last tile
#define LK 8              // per-lane sorted key slots
#define SLC 16            // per (row,slice) stored candidates (2 lanes x LK)
#define CAND 256          // NSLICE * SLC per row per task
#define K1W 4             // waves per k1 block (tile-split, LDS-merged)

// out layout (floats): vals_cos, ind_cos, labels_rot, vals_euc, ind_euc, labels_trans
#define O_VC 0
#define O_IC 40960
#define O_LR 81920
#define O_VE 122880
#define O_IE 163840
#define O_LT 204800

// ws layout (bytes): Bbf (fragment-ordered, padded) 25.69MB | bq2 200KB | candU 2.1MB
#define WS_BBF   0
#define WS_BQ2   25690112
#define WS_CAND  25890112

// k2 staging stride: 132 floats = 528 B (16B multiple -> aligned ds_write_b128;
// 132 % 32 = 4 -> per-row bank rotation, scalar column reads <=2-way conflict = free)
#define BSTR 132

typedef short v8s __attribute__((ext_vector_type(8)));
typedef float v16f __attribute__((ext_vector_type(16)));

union U4V8 { uint4 u; v8s v; };

__device__ __forceinline__ unsigned int bf16rne(float f) {
    unsigned int x = __float_as_uint(f);
    return (x + 0x7FFFu + ((x >> 16) & 1u)) >> 16;
}
// monotone fp32 -> u32 (total order)
__device__ __forceinline__ unsigned int sortkey(float s) {
    unsigned int b = __float_as_uint(s);
    return b ^ ((unsigned int)((int)b >> 31) | 0x80000000u);
}
// single-instruction sorted-insert step: med3(k, key[u], key[u+1]) ==
// min(key[u+1], max(k, key[u])) under the sortedness invariant key[u] <= key[u+1]
__device__ __forceinline__ unsigned int med3u(unsigned int a, unsigned int b, unsigned int c) {
    unsigned int d;
    asm("v_med3_u32 %0, %1, %2, %3" : "=v"(d) : "v"(a), "v"(b), "v"(c));
    return d;
}
// low-register-pressure top-8 insert (consumes one key at a time; run ascending)
__device__ __forceinline__ void ins8(unsigned int (&run)[LK], unsigned int k) {
    #pragma unroll
    for (int u = 0; u < LK - 1; u++) run[u] = med3u(k, run[u], run[u + 1]);
    run[LK - 1] = max(k, run[LK - 1]);
}
// compare-exchange (for the block-merge network only)
__device__ __forceinline__ void ce(unsigned int &a, unsigned int &b) {
    unsigned int lo = min(a, b);
    unsigned int hi = max(a, b);
    a = lo; b = hi;
}
// run asc, s asc -> run = top-8 of (run ∪ s), ascending (8 max + 12-CE bitonic)
__device__ __forceinline__ void merge8(unsigned int (&run)[LK], const unsigned int* s) {
    unsigned int m[8];
    #pragma unroll
    for (int i = 0; i < 8; i++) m[i] = max(run[i], s[7 - i]);
    ce(m[0],m[4]); ce(m[1],m[5]); ce(m[2],m[6]); ce(m[3],m[7]);
    ce(m[0],m[2]); ce(m[1],m[3]); ce(m[4],m[6]); ce(m[5],m[7]);
    ce(m[0],m[1]); ce(m[2],m[3]); ce(m[4],m[5]); ce(m[6],m[7]);
    #pragma unroll
    for (int i = 0; i < 8; i++) run[i] = m[i];
}

// ---------------- K0: build bf16 book in MFMA-FRAGMENT ORDER + packed -bq ----------
__global__ __launch_bounds__(256) void k_cvt2(const float* __restrict__ bR,
                                              const float* __restrict__ bT,
                                              unsigned int* __restrict__ Bbf,
                                              unsigned int* __restrict__ bq2)
{
    const int tile  = blockIdx.x;   // 0..97
    const int slice = blockIdx.y;   // 0..15
    const int task  = blockIdx.z;
    const int t = threadIdx.x;
    const float* __restrict__ src = task ? bT : bR;
    const float sc = task ? 2.f : 1.f;

    __shared__ float ps[4][64];

    unsigned int* tb = Bbf + (((size_t)(task * NSLICE + slice) * NTILE + tile) << 11);

    float partial = 0.f;
    #pragma unroll
    for (int half = 0; half < 2; half++) {
        const int x = t + half * 256;
        const int c = x & 31, hh = (x >> 5) & 1, q = x >> 6;
        const int es = slice * NSL + min(tile * 32 + c, NSL - 1);
        const float* p = src + (size_t)es * DD + q * 16 + hh * 8;
        float4 u0 = *reinterpret_cast<const float4*>(p);
        float4 u1 = *reinterpret_cast<const float4*>(p + 4);
        partial += u0.x * u0.x + u0.y * u0.y + u0.z * u0.z + u0.w * u0.w
                 + u1.x * u1.x + u1.y * u1.y + u1.z * u1.z + u1.w * u1.w;
        uint4 o;
        o.x = bf16rne(u0.x * sc) | (bf16rne(u0.y * sc) << 16);
        o.y = bf16rne(u0.z * sc) | (bf16rne(u0.w * sc) << 16);
        o.z = bf16rne(u1.x * sc) | (bf16rne(u1.y * sc) << 16);
        o.w = bf16rne(u1.z * sc) | (bf16rne(u1.w * sc) << 16);
        *reinterpret_cast<uint4*>(tb + (q << 8) + hh * 128 + c * 4) = o;
    }

    if (task) {
        ps[t >> 6][t & 63] = partial;
        __syncthreads();
        if (t < 32) {
            float sq = 0.f;
            #pragma unroll
            for (int w2 = 0; w2 < 4; w2++) sq += ps[w2][t] + ps[w2][t + 32];
            unsigned int hi = bf16rne(sq);
            float fhi = __uint_as_float(hi << 16);
            unsigned int lo = bf16rne(sq - fhi);
            const int e = slice * NSL + min(tile * 32 + t, NSL - 1);
            bq2[e] = (hi ^ 0x8000u) | ((lo ^ 0x8000u) << 16);  // packed (-bq_hi, -bq_lo)
        }
    }
}

// ---------------- K1: MFMA scoring, z-frags in LDS, med3-chain top-8 (as R4) -------
__global__ __launch_bounds__(256, 8) void k1_sel(
    const float* __restrict__ zR, const float* __restrict__ zT,
    const unsigned int* __restrict__ Bbf,
    const unsigned int* __restrict__ bq2,
    uint4* __restrict__ candU)
{
    const int slice = blockIdx.x;       // 0..15
    const int rg    = blockIdx.y;       // 0..63
    const int task  = blockIdx.z;
    const int w     = threadIdx.x >> 6; // wave 0..3
    const int lane  = threadIdx.x & 63;
    const int col   = lane & 31;
    const int h     = lane >> 5;

    __shared__ uint4 zs[8][64];                         // 8 KB shared z-frags
    __shared__ unsigned int smk[K1W - 1][64][LK + 1];   // stride-9 pad, 6.75 KB

    if (w == 0) {
        const float* zp = (task ? zT : zR) + (size_t)(rg * 32 + col) * DD;
        #pragma unroll
        for (int q = 0; q < 8; q++) {
            float4 u0 = *reinterpret_cast<const float4*>(zp + q * 16 + h * 8);
            float4 u1 = *reinterpret_cast<const float4*>(zp + q * 16 + h * 8 + 4);
            uint4 c;
            c.x = bf16rne(u0.x) | (bf16rne(u0.y) << 16);
            c.y = bf16rne(u0.z) | (bf16rne(u0.w) << 16);
            c.z = bf16rne(u1.x) | (bf16rne(u1.y) << 16);
            c.w = bf16rne(u1.z) | (bf16rne(u1.w) << 16);
            zs[q][lane] = c;
        }
    }
    U4V8 zf8; zf8.u = make_uint4(h == 0 ? 0x3F803F80u : 0u, 0u, 0u, 0u);
    __syncthreads();

    unsigned int run[LK];
    #pragma unroll
    for (int u = 0; u < LK; u++) run[u] = 0u;

    const int nbase0 = slice * NSL;
    const unsigned int* bp = Bbf + ((size_t)(task * NSLICE + slice) * NTILE << 11) + lane * 4;

#define TILE_BODY(TILE, TAIL)                                                          \
    {                                                                                  \
        asm volatile("" ::: "memory");  /* keep zs reads per-tile (no 32-reg hoist) */ \
        const unsigned int* tb = bp + ((size_t)(TILE) << 11);                          \
        v16f acc = {0.f,0.f,0.f,0.f, 0.f,0.f,0.f,0.f,                                  \
                    0.f,0.f,0.f,0.f, 0.f,0.f,0.f,0.f};                                 \
        _Pragma("unroll")                                                              \
        for (int q = 0; q < 8; q++) {                                                  \
            U4V8 a; a.u = *reinterpret_cast<const uint4*>(tb + (q << 8));              \
            U4V8 z; z.u = zs[q][lane];                                                 \
            acc = __builtin_amdgcn_mfma_f32_32x32x16_bf16(a.v, z.v, acc, 0, 0, 0);     \
        }                                                                              \
        if (task) {                                                                    \
            int e = nbase0 + (TILE) * 32 + col;                                        \
            if (TAIL) e = min(e, nbase0 + NSL - 1);                                    \
            unsigned int bqp = bq2[e];                                                 \
            U4V8 a; a.u = make_uint4(h == 0 ? bqp : 0u, 0u, 0u, 0u);                   \
            acc = __builtin_amdgcn_mfma_f32_32x32x16_bf16(a.v, zf8.v, acc, 0, 0, 0);   \
        }                                                                              \
        const int nb = nbase0 + (TILE) * 32 + 4 * h;                                   \
        _Pragma("unroll")                                                              \
        for (int r = 0; r < 16; r++) {                                                 \
            const int pat = (r & 3) + 8 * (r >> 2);                                    \
            const int n = nb + pat;                                                    \
            unsigned int k = (sortkey(acc[r]) & 0xFFFF0000u) | (unsigned int)n;        \
            if (TAIL && (pat + 4 * h >= TAILV)) k = 0u;                                \
            ins8(run, k);                                                              \
        }                                                                              \
    }

    int tile = w;
    for (; tile < NTILE - 1; tile += K1W) TILE_BODY(tile, 0)
    if (tile == NTILE - 1) TILE_BODY(tile, 1)
#undef TILE_BODY

    if (w > 0) {
        #pragma unroll
        for (int u = 0; u < LK; u++) smk[w - 1][lane][u] = run[u];
    }
    __syncthreads();
    if (w == 0) {
        #pragma unroll
        for (int v = 0; v < K1W - 1; v++) {
            unsigned int s[LK];
            #pragma unroll
            for (int u = 0; u < LK; u++) s[u] = smk[v][lane][u];
            merge8(run, s);
        }

        uint4 o;
        o.x = (run[0] & 0xFFFFu) | ((run[1] & 0xFFFFu) << 16);
        o.y = (run[2] & 0xFFFFu) | ((run[3] & 0xFFFFu) << 16);
        o.z = (run[4] & 0xFFFFu) | ((run[5] & 0xFFFFu) << 16);
        o.w = (run[6] & 0xFFFFu) | ((run[7] & 0xFFFFu) << 16);
        const int row = rg * 32 + col;
        candU[((size_t)(task * BB + row) * NSLICE + slice) * 2 + h] = o;
    }
}

// ---------------- K2: exact final ranking + gather, LDS-staged candidate rows ------
// R4 post-mortem: k2 was a latency-bound random gather (256 random 512B rows/block,
// VALUBusy 15%, occupancy 26%, nothing saturated). Fix: cooperative coalesced staging
// of 64-row chunks into padded LDS (stride BSTR=132 floats: 528B = 16B-aligned for
// ds_write_b128, and row-rotated banks for the scalar column reads), then rescore from
// LDS. euc split 4 threads/candidate with bit-identical __fadd_rn trees (IEEE add
// commutative => lane order immaterial). cos keeps the identical idx/part/shfl
// structure. Selection phases untouched => output bit-identical.
__global__ __launch_bounds__(256) void k2_final(
    const float* __restrict__ Zr, const float* __restrict__ Zt,
    const float* __restrict__ Br, const float* __restrict__ Bt,
    const float* __restrict__ rotB, const float* __restrict__ transB,
    const unsigned short* __restrict__ candU16,
    float* __restrict__ out)
{
    const int row = blockIdx.x;
    const int task = blockIdx.y;
    const int t = threadIdx.x;
    const float* __restrict__ Z  = task ? Zt : Zr;
    const float* __restrict__ Bk = task ? Bt : Br;

    __shared__ __align__(16) float zrow[DD];
    __shared__ int sel[CAND];
    __shared__ double dsum[CAND];
    __shared__ double sval[KK];
    __shared__ int sidx[KK];
    __shared__ float sv[CAND];
    __shared__ __align__(16) float buf[64 * BSTR];   // 64 rows, 528B stride (33.75 KB)

    if (t < DD) zrow[t] = Z[(size_t)row * DD + t];
    sel[t] = (int)candU16[((size_t)task * BB + row) * CAND + t];
    __syncthreads();

    const int sr = t >> 2;   // staging row within chunk (also euc candidate)
    const int sg = t & 3;    // staging segment / euc component j

    for (int c = 0; c < 4; ++c) {
        // ---- stage 64 candidate rows (512B each) into padded LDS, coalesced ----
        {
            const int n = sel[c * 64 + sr];
            const float* src = Bk + (size_t)n * DD + sg * 32;
            float4 tmp[8];
            #pragma unroll
            for (int i = 0; i < 8; i++)
                tmp[i] = *reinterpret_cast<const float4*>(src + i * 4);
            #pragma unroll
            for (int i = 0; i < 8; i++)
                *reinterpret_cast<float4*>(&buf[sr * BSTR + sg * 32 + i * 4]) = tmp[i];
        }
        __syncthreads();

        if (task == 0) {
            // ---- cos: exact fp64 rescore (identical op tree; reads from LDS) ----
            #pragma unroll
            for (int sub = 0; sub < 2; sub++) {
                const int idx = c * 512 + sub * 256 + t;
                const int cnd = idx >> 3, part = idx & 7;
                const float* brow = &buf[(cnd - c * 64) * BSTR + part * 16];
                double dp = 0.0;
                #pragma unroll
                for (int q = 0; q < 4; q++) {
                    float4 b4 = *reinterpret_cast<const float4*>(brow + q * 4);
                    const int k = part * 16 + q * 4;
                    dp += (double)zrow[k + 0] * (double)b4.x + (double)zrow[k + 1] * (double)b4.y
                        + (double)zrow[k + 2] * (double)b4.z + (double)zrow[k + 3] * (double)b4.w;
                }
                dp += __shfl_xor(dp, 1, 64);
                dp += __shfl_xor(dp, 2, 64);
                dp += __shfl_xor(dp, 4, 64);
                if ((t & 7) == 0) dsum[cnd] = dp;
            }
        } else {
            // ---- euc: bit-exact numpy-fp32, 4 threads/candidate from LDS ----
            // component j = sg of candidate sr; chains identical to the serial version.
            const float* brow = &buf[sr * BSTR];
            float L = 0.f, rA = 0.f, rB = 0.f, qA = 0.f, qB = 0.f;
            #pragma unroll
            for (int c4 = 0; c4 < 32; c4++) {
                const float b = brow[c4 * 4 + sg];
                const float z = zrow[c4 * 4 + sg];
                L = __fadd_rn(L, __fmul_rn(z, b));
                if ((c4 & 1) == 0) {
                    rA = __fadd_rn(rA, __fmul_rn(b, b));
                    qA = __fadd_rn(qA, __fmul_rn(z, z));
                } else {
                    rB = __fadd_rn(rB, __fmul_rn(b, b));
                    qB = __fadd_rn(qB, __fmul_rn(z, z));
                }
            }
            // dot = (L0+L2)+(L1+L3)   (fp add commutative -> same value on all 4 lanes)
            float a2 = __fadd_rn(L, __shfl_xor(L, 2, 64));
            float dot = __fadd_rn(a2, __shfl_xor(a2, 1, 64));
            // bqv = ((r0+r1)+(r2+r3)) + ((r4+r5)+(r6+r7))
            float s1 = __fadd_rn(rA, __shfl_xor(rA, 1, 64));
            float u1 = __fadd_rn(s1, __shfl_xor(s1, 2, 64));
            float s2 = __fadd_rn(rB, __shfl_xor(rB, 1, 64));
            float u2 = __fadd_rn(s2, __shfl_xor(s2, 2, 64));
            const float bqv = __fadd_rn(u1, u2);
            // zqv identical structure from q chains
            float s3 = __fadd_rn(qA, __shfl_xor(qA, 1, 64));
            float u3 = __fadd_rn(s3, __shfl_xor(s3, 2, 64));
            float s4 = __fadd_rn(qB, __shfl_xor(qB, 1, 64));
            float u4 = __fadd_rn(s4, __shfl_xor(s4, 2, 64));
            const float zqv = __fadd_rn(u3, u4);
            if (sg == 0)
                sv[c * 64 + sr] = __fsub_rn(__fsub_rn(__fmul_rn(2.0f, dot), zqv), bqv);
        }
        __syncthreads();
    }

    if (task == 0) {
        if (t < 64) {
            double zq = (double)zrow[t] * (double)zrow[t]
                      + (double)zrow[t + 64] * (double)zrow[t + 64];
            #pragma unroll
            for (int m = 1; m < 64; m <<= 1) zq += __shfl_xor(zq, m, 64);

            double s[4]; int ix[4];
            #pragma unroll
            for (int j = 0; j < 4; j++) {
                const int cc = t + 64 * j;
                s[j] = dsum[cc]; ix[j] = sel[cc];
            }

            for (int rd = 0; rd < KK; rd++) {
                double bs = s[0]; int bn = ix[0];
                #pragma unroll
                for (int j = 1; j < 4; j++)
                    if (s[j] > bs || (s[j] == bs && ix[j] < bn)) { bs = s[j]; bn = ix[j]; }
                #pragma unroll
                for (int m = 1; m < 64; m <<= 1) {
                    double os = __shfl_xor(bs, m, 64);
                    int on = __shfl_xor(bn, m, 64);
                    if (os > bs || (os == bs && on < bn)) { bs = os; bn = on; }
                }
                #pragma unroll
                for (int j = 0; j < 4; j++) if (ix[j] == bn) s[j] = -DBL_MAX;
                if (t == 0) { sval[rd] = bs; sidx[rd] = bn; }
            }
            if (t == 0) dsum[0] = zq;
        }
        __syncthreads();

        if (t < KK) {
            const double zq = dsum[0];
            const int n = sidx[t];
            const int o = row * KK + t;
            out[O_VC + o] = (float)(sval[t] / sqrt(zq));
            out[O_IC + o] = (float)n;
            out[O_LR + o] = rotB[n];
        }
    } else {
        if (t < 64) {
            float s[4]; int ix[4];
            #pragma unroll
            for (int j = 0; j < 4; j++) { s[j] = sv[t + 64 * j]; ix[j] = sel[t + 64 * j]; }

            for (int rd = 0; rd < KK; rd++) {
                float bs = s[0]; int bn = ix[0];
                #pragma unroll
                for (int j = 1; j < 4; j++)
                    if (s[j] > bs || (s[j] == bs && ix[j] < bn)) { bs = s[j]; bn = ix[j]; }
                #pragma unroll
                for (int m = 1; m < 64; m <<= 1) {
                    float os = __shfl_xor(bs, m, 64);
                    int on = __shfl_xor(bn, m, 64);
                    if (os > bs || (os == bs && on < bn)) { bs = os; bn = on; }
                }
                #pragma unroll
                for (int j = 0; j < 4; j++) if (ix[j] == bn) s[j] = -FLT_MAX;
                if (t == 0) {
                    const int o = row * KK + rd;
                    out[O_VE + o] = bs;
                    out[O_IE + o] = (float)bn;
                    const int o3 = O_LT + o * 3;
                    out[o3 + 0] = transB[bn * 3 + 0];
                    out[o3 + 1] = transB[bn * 3 + 1];
                    out[o3 + 2] = transB[bn * 3 + 2];
                }
            }
        }
    }
}

// ---------------- launch ------------------------------------------------------------
extern "C" void kernel_launch(void* const* d_in, const int* in_sizes, int n_in,
                              void* d_out, int out_size, void* d_ws, size_t ws_size,
                              hipStream_t stream) {
    const float* zR = (const float*)d_in[0];
    const float* zT = (const float*)d_in[1];
    const float* bR = (const float*)d_in[2];
    const float* bT = (const float*)d_in[3];
    const float* rotB = (const float*)d_in[4];
    const float* transB = (const float*)d_in[5];
    float* out = (float*)d_out;

    char* ws = (char*)d_ws;
    unsigned int* Bbf = (unsigned int*)(ws + WS_BBF);
    unsigned int* bq2 = (unsigned int*)(ws + WS_BQ2);
    uint4* candU = (uint4*)(ws + WS_CAND);

    k_cvt2<<<dim3(NTILE, NSLICE, 2), 256, 0, stream>>>(bR, bT, Bbf, bq2);
    k1_sel<<<dim3(NSLICE, 64, 2), 256, 0, stream>>>(zR, zT, Bbf, bq2, candU);
    k2_final<<<dim3(BB, 2), 256, 0, stream>>>(zR, zT, bR, bT, rotB, transB,
                                              (const unsigned short*)candU, out);
}

// Round 7
// 328.417 us; speedup vs baseline: 1.3595x; 1.0214x over previous
//
#include <hip/hip_runtime.h>
#include <cfloat>
#include <climits>
#include <math.h>

// Problem constants
#define BB 2048
#define NN 50000
#define DD 128
#define KK 20

// K1 selection geometry
#define NSLICE 16
#define NSL 3125          // NN / NSLICE (exact)
#define NTILE 98          // ceil(NSL/32); tile 97 partial (21 valid entries)
#define TAILV 21          // NSL - (NTILE-1)*32 valid entries in last tile
#define LK 8              // per-lane sorted key slots
#define SLC 16            // per (row,slice) stored candidates (2 lanes x LK)
#define CAND 256          // NSLICE * SLC per row per task
#define K1W 4             // waves per k1 block (tile-split, LDS-merged)

// out layout (floats): vals_cos, ind_cos, labels_rot, vals_euc, ind_euc, labels_trans
#define O_VC 0
#define O_IC 40960
#define O_LR 81920
#define O_VE 122880
#define O_IE 163840
#define O_LT 204800

// ws layout (bytes): Bbf (fragment-ordered, padded) 25.69MB | bq2 200KB | candU 2.1MB
#define WS_BBF   0
#define WS_BQ2   25690112
#define WS_CAND  25890112
// k2 score scratch ALIASES the Bbf region: k2a runs stream-ordered after k1_sel's
// last read of Bbf, and k_cvt2 rewrites Bbf at the start of every launch. Safe.
#define WS_DSUM  0          // 2048*256*8B = 4.19 MB (fp64 cos rescores)
#define WS_SV    4194304    // 2048*256*4B = 2.10 MB (fp32 euc rescores)

typedef short v8s __attribute__((ext_vector_type(8)));
typedef float v16f __attribute__((ext_vector_type(16)));

union U4V8 { uint4 u; v8s v; };

__device__ __forceinline__ unsigned int bf16rne(float f) {
    unsigned int x = __float_as_uint(f);
    return (x + 0x7FFFu + ((x >> 16) & 1u)) >> 16;
}
// monotone fp32 -> u32 (total order)
__device__ __forceinline__ unsigned int sortkey(float s) {
    unsigned int b = __float_as_uint(s);
    return b ^ ((unsigned int)((int)b >> 31) | 0x80000000u);
}
// single-instruction sorted-insert step: med3(k, key[u], key[u+1]) ==
// min(key[u+1], max(k, key[u])) under the sortedness invariant key[u] <= key[u+1]
__device__ __forceinline__ unsigned int med3u(unsigned int a, unsigned int b, unsigned int c) {
    unsigned int d;
    asm("v_med3_u32 %0, %1, %2, %3" : "=v"(d) : "v"(a), "v"(b), "v"(c));
    return d;
}
// low-register-pressure top-8 insert (consumes one key at a time; run ascending)
__device__ __forceinline__ void ins8(unsigned int (&run)[LK], unsigned int k) {
    #pragma unroll
    for (int u = 0; u < LK - 1; u++) run[u] = med3u(k, run[u], run[u + 1]);
    run[LK - 1] = max(k, run[LK - 1]);
}
// compare-exchange (for the block-merge network only)
__device__ __forceinline__ void ce(unsigned int &a, unsigned int &b) {
    unsigned int lo = min(a, b);
    unsigned int hi = max(a, b);
    a = lo; b = hi;
}
// run asc, s asc -> run = top-8 of (run ∪ s), ascending (8 max + 12-CE bitonic)
__device__ __forceinline__ void merge8(unsigned int (&run)[LK], const unsigned int* s) {
    unsigned int m[8];
    #pragma unroll
    for (int i = 0; i < 8; i++) m[i] = max(run[i], s[7 - i]);
    ce(m[0],m[4]); ce(m[1],m[5]); ce(m[2],m[6]); ce(m[3],m[7]);
    ce(m[0],m[2]); ce(m[1],m[3]); ce(m[4],m[6]); ce(m[5],m[7]);
    ce(m[0],m[1]); ce(m[2],m[3]); ce(m[4],m[5]); ce(m[6],m[7]);
    #pragma unroll
    for (int i = 0; i < 8; i++) run[i] = m[i];
}

// ---------------- K0: build bf16 book in MFMA-FRAGMENT ORDER + packed -bq ----------
__global__ __launch_bounds__(256) void k_cvt2(const float* __restrict__ bR,
                                              const float* __restrict__ bT,
                                              unsigned int* __restrict__ Bbf,
                                              unsigned int* __restrict__ bq2)
{
    const int tile  = blockIdx.x;   // 0..97
    const int slice = blockIdx.y;   // 0..15
    const int task  = blockIdx.z;
    const int t = threadIdx.x;
    const float* __restrict__ src = task ? bT : bR;
    const float sc = task ? 2.f : 1.f;

    __shared__ float ps[4][64];

    unsigned int* tb = Bbf + (((size_t)(task * NSLICE + slice) * NTILE + tile) << 11);

    float partial = 0.f;
    #pragma unroll
    for (int half = 0; half < 2; half++) {
        const int x = t + half * 256;
        const int c = x & 31, hh = (x >> 5) & 1, q = x >> 6;
        const int es = slice * NSL + min(tile * 32 + c, NSL - 1);
        const float* p = src + (size_t)es * DD + q * 16 + hh * 8;
        float4 u0 = *reinterpret_cast<const float4*>(p);
        float4 u1 = *reinterpret_cast<const float4*>(p + 4);
        partial += u0.x * u0.x + u0.y * u0.y + u0.z * u0.z + u0.w * u0.w
                 + u1.x * u1.x + u1.y * u1.y + u1.z * u1.z + u1.w * u1.w;
        uint4 o;
        o.x = bf16rne(u0.x * sc) | (bf16rne(u0.y * sc) << 16);
        o.y = bf16rne(u0.z * sc) | (bf16rne(u0.w * sc) << 16);
        o.z = bf16rne(u1.x * sc) | (bf16rne(u1.y * sc) << 16);
        o.w = bf16rne(u1.z * sc) | (bf16rne(u1.w * sc) << 16);
        *reinterpret_cast<uint4*>(tb + (q << 8) + hh * 128 + c * 4) = o;
    }

    if (task) {
        ps[t >> 6][t & 63] = partial;
        __syncthreads();
        if (t < 32) {
            float sq = 0.f;
            #pragma unroll
            for (int w2 = 0; w2 < 4; w2++) sq += ps[w2][t] + ps[w2][t + 32];
            unsigned int hi = bf16rne(sq);
            float fhi = __uint_as_float(hi << 16);
            unsigned int lo = bf16rne(sq - fhi);
            const int e = slice * NSL + min(tile * 32 + t, NSL - 1);
            bq2[e] = (hi ^ 0x8000u) | ((lo ^ 0x8000u) << 16);  // packed (-bq_hi, -bq_lo)
        }
    }
}

// ---------------- K1: MFMA scoring, z-frags in LDS, med3-chain top-8 (as R4) -------
__global__ __launch_bounds__(256, 8) void k1_sel(
    const float* __restrict__ zR, const float* __restrict__ zT,
    const unsigned int* __restrict__ Bbf,
    const unsigned int* __restrict__ bq2,
    uint4* __restrict__ candU)
{
    const int slice = blockIdx.x;       // 0..15
    const int rg    = blockIdx.y;       // 0..63
    const int task  = blockIdx.z;
    const int w     = threadIdx.x >> 6; // wave 0..3
    const int lane  = threadIdx.x & 63;
    const int col   = lane & 31;
    const int h     = lane >> 5;

    __shared__ uint4 zs[8][64];                         // 8 KB shared z-frags
    __shared__ unsigned int smk[K1W - 1][64][LK + 1];   // stride-9 pad, 6.75 KB

    if (w == 0) {
        const float* zp = (task ? zT : zR) + (size_t)(rg * 32 + col) * DD;
        #pragma unroll
        for (int q = 0; q < 8; q++) {
            float4 u0 = *reinterpret_cast<const float4*>(zp + q * 16 + h * 8);
            float4 u1 = *reinterpret_cast<const float4*>(zp + q * 16 + h * 8 + 4);
            uint4 c;
            c.x = bf16rne(u0.x) | (bf16rne(u0.y) << 16);
            c.y = bf16rne(u0.z) | (bf16rne(u0.w) << 16);
            c.z = bf16rne(u1.x) | (bf16rne(u1.y) << 16);
            c.w = bf16rne(u1.z) | (bf16rne(u1.w) << 16);
            zs[q][lane] = c;
        }
    }
    U4V8 zf8; zf8.u = make_uint4(h == 0 ? 0x3F803F80u : 0u, 0u, 0u, 0u);
    __syncthreads();

    unsigned int run[LK];
    #pragma unroll
    for (int u = 0; u < LK; u++) run[u] = 0u;

    const int nbase0 = slice * NSL;
    const unsigned int* bp = Bbf + ((size_t)(task * NSLICE + slice) * NTILE << 11) + lane * 4;

#define TILE_BODY(TILE, TAIL)                                                          \
    {                                                                                  \
        asm volatile("" ::: "memory");  /* keep zs reads per-tile (no 32-reg hoist) */ \
        const unsigned int* tb = bp + ((size_t)(TILE) << 11);                          \
        v16f acc = {0.f,0.f,0.f,0.f, 0.f,0.f,0.f,0.f,                                  \
                    0.f,0.f,0.f,0.f, 0.f,0.f,0.f,0.f};                                 \
        _Pragma("unroll")                                                              \
        for (int q = 0; q < 8; q++) {                                                  \
            U4V8 a; a.u = *reinterpret_cast<const uint4*>(tb + (q << 8));              \
            U4V8 z; z.u = zs[q][lane];                                                 \
            acc = __builtin_amdgcn_mfma_f32_32x32x16_bf16(a.v, z.v, acc, 0, 0, 0);     \
        }                                                                              \
        if (task) {                                                                    \
            int e = nbase0 + (TILE) * 32 + col;                                        \
            if (TAIL) e = min(e, nbase0 + NSL - 1);                                    \
            unsigned int bqp = bq2[e];                                                 \
            U4V8 a; a.u = make_uint4(h == 0 ? bqp : 0u, 0u, 0u, 0u);                   \
            acc = __builtin_amdgcn_mfma_f32_32x32x16_bf16(a.v, zf8.v, acc, 0, 0, 0);   \
        }                                                                              \
        const int nb = nbase0 + (TILE) * 32 + 4 * h;                                   \
        _Pragma("unroll")                                                              \
        for (int r = 0; r < 16; r++) {                                                 \
            const int pat = (r & 3) + 8 * (r >> 2);                                    \
            const int n = nb + pat;                                                    \
            unsigned int k = (sortkey(acc[r]) & 0xFFFF0000u) | (unsigned int)n;        \
            if (TAIL && (pat + 4 * h >= TAILV)) k = 0u;                                \
            ins8(run, k);                                                              \
        }                                                                              \
    }

    int tile = w;
    for (; tile < NTILE - 1; tile += K1W) TILE_BODY(tile, 0)
    if (tile == NTILE - 1) TILE_BODY(tile, 1)
#undef TILE_BODY

    if (w > 0) {
        #pragma unroll
        for (int u = 0; u < LK; u++) smk[w - 1][lane][u] = run[u];
    }
    __syncthreads();
    if (w == 0) {
        #pragma unroll
        for (int v = 0; v < K1W - 1; v++) {
            unsigned int s[LK];
            #pragma unroll
            for (int u = 0; u < LK; u++) s[u] = smk[v][lane][u];
            merge8(run, s);
        }

        uint4 o;
        o.x = (run[0] & 0xFFFFu) | ((run[1] & 0xFFFFu) << 16);
        o.y = (run[2] & 0xFFFFu) | ((run[3] & 0xFFFFu) << 16);
        o.z = (run[4] & 0xFFFFu) | ((run[5] & 0xFFFFu) << 16);
        o.w = (run[6] & 0xFFFFu) | ((run[7] & 0xFFFFu) << 16);
        const int row = rg * 32 + col;
        candU[((size_t)(task * BB + row) * NSLICE + slice) * 2 + h] = o;
    }
}

// ---------------- K2a: rescore, fully parallel, no LDS, no barriers ----------------
// R6 post-mortem: bulk-synchronous LDS staging kept k2 latency-bound (occupancy 30%,
// VALUBusy 17%, +13M bank conflicts from the staging stride). Fix: one block per
// (row, 64-cand chunk, task), 4 threads/candidate reading straight from global with
// deep MLP, shfl-reduced, scores to workspace. 16K independent blocks + tiny register/
// LDS footprint -> latency hidden by wave parallelism instead of intra-block phases.
// euc chains are the R6-verified bit-exact component-split (same fp32 bits from
// global as from LDS); cos fp64 reassociation is ~1e-16, invisible after fp32 round.
__global__ __launch_bounds__(256) void k2a_rescore(
    const float* __restrict__ Zr, const float* __restrict__ Zt,
    const float* __restrict__ Br, const float* __restrict__ Bt,
    const unsigned short* __restrict__ candU16,
    double* __restrict__ dsumW, float* __restrict__ svW)
{
    const int row   = blockIdx.x;
    const int chunk = blockIdx.y;   // 0..3
    const int task  = blockIdx.z;
    const int t  = threadIdx.x;
    const int sr = t >> 2;          // candidate within chunk (0..63)
    const int sg = t & 3;           // sub-thread / component
    const int cidx = chunk * 64 + sr;
    const int n = (int)candU16[((size_t)task * BB + row) * CAND + cidx];

    if (task == 0) {
        // ---- cos: fp64 rescore, 4 threads x 32 dims, 2-level shfl reduce ----
        const float* brow = Br + (size_t)n * DD + sg * 32;
        const float* zrow = Zr + (size_t)row * DD + sg * 32;
        double dp = 0.0;
        #pragma unroll
        for (int q = 0; q < 8; q++) {
            float4 b4 = *reinterpret_cast<const float4*>(brow + q * 4);
            float4 z4 = *reinterpret_cast<const float4*>(zrow + q * 4);
            dp += (double)z4.x * (double)b4.x + (double)z4.y * (double)b4.y
                + (double)z4.z * (double)b4.z + (double)z4.w * (double)b4.w;
        }
        dp += __shfl_xor(dp, 1, 64);
        dp += __shfl_xor(dp, 2, 64);
        if (sg == 0) dsumW[(size_t)row * CAND + cidx] = dp;
    } else {
        // ---- euc: bit-exact numpy-fp32 component-split chains (verified R6) ----
        const float* brow = Bt + (size_t)n * DD;
        const float* zrow = Zt + (size_t)row * DD;
        float L = 0.f, rA = 0.f, rB = 0.f, qA = 0.f, qB = 0.f;
        #pragma unroll
        for (int c4 = 0; c4 < 32; c4++) {
            const float b = brow[c4 * 4 + sg];
            const float z = zrow[c4 * 4 + sg];
            L = __fadd_rn(L, __fmul_rn(z, b));
            if ((c4 & 1) == 0) {
                rA = __fadd_rn(rA, __fmul_rn(b, b));
                qA = __fadd_rn(qA, __fmul_rn(z, z));
            } else {
                rB = __fadd_rn(rB, __fmul_rn(b, b));
                qB = __fadd_rn(qB, __fmul_rn(z, z));
            }
        }
        // dot = (L0+L2)+(L1+L3)  (fp add commutative -> same value on all 4 lanes)
        float a2 = __fadd_rn(L, __shfl_xor(L, 2, 64));
        float dot = __fadd_rn(a2, __shfl_xor(a2, 1, 64));
        // bqv = ((r0+r1)+(r2+r3)) + ((r4+r5)+(r6+r7))
        float s1 = __fadd_rn(rA, __shfl_xor(rA, 1, 64));
        float u1 = __fadd_rn(s1, __shfl_xor(s1, 2, 64));
        float s2 = __fadd_rn(rB, __shfl_xor(rB, 1, 64));
        float u2 = __fadd_rn(s2, __shfl_xor(s2, 2, 64));
        const float bqv = __fadd_rn(u1, u2);
        // zqv identical structure from q chains
        float s3 = __fadd_rn(qA, __shfl_xor(qA, 1, 64));
        float u3 = __fadd_rn(s3, __shfl_xor(s3, 2, 64));
        float s4 = __fadd_rn(qB, __shfl_xor(qB, 1, 64));
        float u4 = __fadd_rn(s4, __shfl_xor(s4, 2, 64));
        const float zqv = __fadd_rn(u3, u4);
        if (sg == 0)
            svW[(size_t)row * CAND + cidx] =
                __fsub_rn(__fsub_rn(__fmul_rn(2.0f, dot), zqv), bqv);
    }
}

// ---------------- K2b: final top-20 selection + label gather (logic unchanged) ------
__global__ __launch_bounds__(64) void k2b_final(
    const float* __restrict__ Zr,
    const float* __restrict__ rotB, const float* __restrict__ transB,
    const unsigned short* __restrict__ candU16,
    const double* __restrict__ dsumW, const float* __restrict__ svW,
    float* __restrict__ out)
{
    const int row = blockIdx.x;
    const int task = blockIdx.y;
    const int t = threadIdx.x;   // 0..63

    __shared__ double sval[KK];
    __shared__ int sidx[KK];

    const unsigned short* selp = candU16 + ((size_t)task * BB + row) * CAND;

    if (task == 0) {
        const float z0 = Zr[(size_t)row * DD + t];
        const float z1 = Zr[(size_t)row * DD + t + 64];
        double zq = (double)z0 * (double)z0 + (double)z1 * (double)z1;
        #pragma unroll
        for (int m = 1; m < 64; m <<= 1) zq += __shfl_xor(zq, m, 64);

        double s[4]; int ix[4];
        #pragma unroll
        for (int j = 0; j < 4; j++) {
            const int cc = t + 64 * j;
            s[j] = dsumW[(size_t)row * CAND + cc];
            ix[j] = (int)selp[cc];
        }

        for (int rd = 0; rd < KK; rd++) {
            double bs = s[0]; int bn = ix[0];
            #pragma unroll
            for (int j = 1; j < 4; j++)
                if (s[j] > bs || (s[j] == bs && ix[j] < bn)) { bs = s[j]; bn = ix[j]; }
            #pragma unroll
            for (int m = 1; m < 64; m <<= 1) {
                double os = __shfl_xor(bs, m, 64);
                int on = __shfl_xor(bn, m, 64);
                if (os > bs || (os == bs && on < bn)) { bs = os; bn = on; }
            }
            #pragma unroll
            for (int j = 0; j < 4; j++) if (ix[j] == bn) s[j] = -DBL_MAX;  // pop
            if (t == 0) { sval[rd] = bs; sidx[rd] = bn; }
        }
        __syncthreads();

        if (t < KK) {
            const int n = sidx[t];
            const int o = row * KK + t;
            out[O_VC + o] = (float)(sval[t] / sqrt(zq));
            out[O_IC + o] = (float)n;
            out[O_LR + o] = rotB[n];
        }
    } else {
        float s[4]; int ix[4];
        #pragma unroll
        for (int j = 0; j < 4; j++) {
            const int cc = t + 64 * j;
            s[j] = svW[(size_t)row * CAND + cc];
            ix[j] = (int)selp[cc];
        }

        for (int rd = 0; rd < KK; rd++) {
            float bs = s[0]; int bn = ix[0];
            #pragma unroll
            for (int j = 1; j < 4; j++)
                if (s[j] > bs || (s[j] == bs && ix[j] < bn)) { bs = s[j]; bn = ix[j]; }
            #pragma unroll
            for (int m = 1; m < 64; m <<= 1) {
                float os = __shfl_xor(bs, m, 64);
                int on = __shfl_xor(bn, m, 64);
                if (os > bs || (os == bs && on < bn)) { bs = os; bn = on; }
            }
            #pragma unroll
            for (int j = 0; j < 4; j++) if (ix[j] == bn) s[j] = -FLT_MAX;
            if (t == 0) {
                const int o = row * KK + rd;
                out[O_VE + o] = bs;
                out[O_IE + o] = (float)bn;
                const int o3 = O_LT + o * 3;
                out[o3 + 0] = transB[bn * 3 + 0];
                out[o3 + 1] = transB[bn * 3 + 1];
                out[o3 + 2] = transB[bn * 3 + 2];
            }
        }
    }
}

// ---------------- launch ------------------------------------------------------------
extern "C" void kernel_launch(void* const* d_in, const int* in_sizes, int n_in,
                              void* d_out, int out_size, void* d_ws, size_t ws_size,
                              hipStream_t stream) {
    const float* zR = (const float*)d_in[0];
    const float* zT = (const float*)d_in[1];
    const float* bR = (const float*)d_in[2];
    const float* bT = (const float*)d_in[3];
    const float* rotB = (const float*)d_in[4];
    const float* transB = (const float*)d_in[5];
    float* out = (float*)d_out;

    char* ws = (char*)d_ws;
    unsigned int* Bbf = (unsigned int*)(ws + WS_BBF);
    unsigned int* bq2 = (unsigned int*)(ws + WS_BQ2);
    uint4* candU = (uint4*)(ws + WS_CAND);
    double* dsumW = (double*)(ws + WS_DSUM);   // aliases Bbf (safe: stream-ordered)
    float* svW = (float*)(ws + WS_SV);

    k_cvt2<<<dim3(NTILE, NSLICE, 2), 256, 0, stream>>>(bR, bT, Bbf, bq2);
    k1_sel<<<dim3(NSLICE, 64, 2), 256, 0, stream>>>(zR, zT, Bbf, bq2, candU);
    k2a_rescore<<<dim3(BB, 4, 2), 256, 0, stream>>>(zR, zT, bR, bT,
                                                    (const unsigned short*)candU,
                                                    dsumW, svW);
    k2b_final<<<dim3(BB, 2), 64, 0, stream>>>(zR, rotB, transB,
                                              (const unsigned short*)candU,
                                              dsumW, svW, out);
}